// Round 7
// baseline (152.453 us; speedup 1.0000x reference)
//
#include <hip/hip_runtime.h>
#include <math.h>

constexpr int B_ = 4096, T_ = 200, D_ = 64, NT = 256;
constexpr float NEG_INF_F = -4294967295.0f;  // float32(-2^32+1)

typedef __attribute__((ext_vector_type(8))) __bf16 bf16x8;
typedef __attribute__((ext_vector_type(4))) float f32x4;

__device__ __host__ inline unsigned short f2b_rne(float x) {
    unsigned u = __builtin_bit_cast(unsigned, x);
    u += 0x7FFF + ((u >> 16) & 1);
    return (unsigned short)(u >> 16);
}

__device__ inline unsigned short b16bits(float x) {
    return __builtin_bit_cast(unsigned short, (__bf16)x);
}

__device__ inline bf16x8 pack8(float4 lo, float4 hi) {
    bf16x8 r;
    r[0] = (__bf16)lo.x; r[1] = (__bf16)lo.y; r[2] = (__bf16)lo.z; r[3] = (__bf16)lo.w;
    r[4] = (__bf16)hi.x; r[5] = (__bf16)hi.y; r[6] = (__bf16)hi.z; r[7] = (__bf16)hi.w;
    return r;
}

__device__ inline bf16x8 pack8m(float4 lo, float4 hi, float4 ql, float4 qh) {
    bf16x8 r;
    r[0] = (__bf16)(lo.x * ql.x); r[1] = (__bf16)(lo.y * ql.y);
    r[2] = (__bf16)(lo.z * ql.z); r[3] = (__bf16)(lo.w * ql.w);
    r[4] = (__bf16)(hi.x * qh.x); r[5] = (__bf16)(hi.y * qh.y);
    r[6] = (__bf16)(hi.z * qh.z); r[7] = (__bf16)(hi.w * qh.w);
    return r;
}

// ---------------------------------------------------------------------------
// Fold weights into MFMA-fragment order (bf16). Same layouts as round 3.
// ---------------------------------------------------------------------------
__global__ void fold_weights(const float* __restrict__ W1,
                             const float* __restrict__ W2,
                             unsigned short* __restrict__ w1f,
                             unsigned short* __restrict__ w2f,
                             float* __restrict__ wqf) {
    int i = blockIdx.x * blockDim.x + threadIdx.x;
    if (i < 10240) {
        int j = i & 7, lane = (i >> 3) & 63, nt = (i >> 9) % 5, s = i / 2560;
        int k = s * 32 + (lane >> 4) * 8 + j;
        int n = nt * 16 + (lane & 15);
        float v = (k < 64) ? W1[(64 + k) * 80 + n] - W1[(128 + k) * 80 + n]
                           : W1[(192 + (k - 64)) * 80 + n];
        w1f[i] = f2b_rne(v);
    } else if (i < 14848) {
        int i2 = i - 10240;
        int j = i2 & 7, lane = (i2 >> 3) & 63, nt = (i2 >> 9) % 3, s = i2 / 1536;
        int k = s * 32 + (lane >> 4) * 8 + j;
        int n = nt * 16 + (lane & 15);
        float v = (k < 80 && n < 40) ? W2[k * 40 + n] : 0.f;
        w2f[i2] = f2b_rne(v);
    } else if (i < 19968) {
        int i3 = i - 14848;
        int n = i3 % 80, d = i3 / 80;
        wqf[i3] = W1[d * 80 + n] + W1[(128 + d) * 80 + n];
    }
}

__global__ __launch_bounds__(256)
void hinit_kernel(const float* __restrict__ q, const float* __restrict__ wqf,
                  const float* __restrict__ b1, float* __restrict__ hinit) {
    int i = blockIdx.x * blockDim.x + threadIdx.x;
    if (i >= B_ * 80) return;
    int b = i / 80, n = i - b * 80;
    const float* qr = q + b * 64;
    float acc = b1[n];
    #pragma unroll 8
    for (int d = 0; d < 64; ++d) acc = fmaf(qr[d], wqf[d * 80 + n], acc);
    hinit[i] = acc;
}

// ---------------------------------------------------------------------------
// Main kernel: one wave = one batch row, ONLINE SOFTMAX fused into the tile
// loop — keys are read exactly once (round 6 read them twice: FETCH 208MB),
// and the 200-iteration output tail pass is gone. Defer-max rescale (skip
// o-rescale unless tile max rises; wave-uniform branch). W1 frags in LDS.
// ---------------------------------------------------------------------------
__global__ __launch_bounds__(NT, 2)
void din_attn(const float* __restrict__ q, const float* __restrict__ keys,
              const int* __restrict__ klen, const float* __restrict__ hinit_g,
              const unsigned short* __restrict__ w1f,
              const unsigned short* __restrict__ w2f,
              const float* __restrict__ b2, const float* __restrict__ W3,
              const float* __restrict__ b3, float* __restrict__ out) {
    const int tid = threadIdx.x;
    const int l = tid & 63, wid = tid >> 6, g4 = l >> 4, ln = l & 15;
    const int b = blockIdx.x * 4 + wid;

    alignas(16) __shared__ unsigned short w1s[10240];       // 20.5 KB W1 frags
    alignas(16) __shared__ unsigned short h1c[4][16 * 104]; // 13.3 KB wave-priv
    __shared__ float olds[4][64];                           // 1 KB out staging

    #pragma unroll
    for (int j = 0; j < 5; ++j) {
        int idx = (j * 256 + tid) * 8;
        *(float4*)&w1s[idx] = *(const float4*)&w1f[idx];
    }
    unsigned short* myh1 = h1c[wid];
    #pragma unroll
    for (int r = 0; r < 4; ++r)
        myh1[(g4 * 4 + r) * 104 + 80 + ln] = 0;   // zero pad cols 80..95 once
    __syncthreads();   // w1s ready — the only block barrier

    const int len = klen[b];
    const float b3v = b3[0];

    float hv[5], b2v[3], w3v[3];
    const float* hb = hinit_g + b * 80;
    #pragma unroll
    for (int nt = 0; nt < 5; ++nt) hv[nt] = hb[nt * 16 + ln];
    #pragma unroll
    for (int nt = 0; nt < 3; ++nt) {
        int idx = nt * 16 + ln;
        b2v[nt] = (idx < 40) ? b2[idx] : 0.f;
        w3v[nt] = (idx < 40) ? W3[idx] : 0.f;
    }
    const float* qb = q + b * 64;
    float4 q0  = *(const float4*)(qb + g4 * 8);
    float4 q0b = *(const float4*)(qb + g4 * 8 + 4);
    float4 q1  = *(const float4*)(qb + 32 + g4 * 8);
    float4 q1b = *(const float4*)(qb + 32 + g4 * 8 + 4);

    const float* kb = keys + (size_t)b * 200 * 64;

    // online-softmax running state (m_run wave-uniform; s/o per-lane partials)
    float m_run = NEG_INF_F * 0.125f;
    float s_part = 0.f;
    float4 o0 = {0,0,0,0}, o1 = o0, o2 = o0, o3 = o0;

#define LOADK(tile_, B0_, B1_, B2_, B3_) do {                              \
        int t_ = (tile_) * 16 + ln;                                        \
        int tc_ = t_ < 200 ? t_ : 199;                                     \
        const float* row_ = kb + tc_ * 64;                                 \
        B0_ = *(const float4*)(row_ + g4 * 8);                             \
        B1_ = *(const float4*)(row_ + g4 * 8 + 4);                         \
        B2_ = *(const float4*)(row_ + 32 + g4 * 8);                        \
        B3_ = *(const float4*)(row_ + 32 + g4 * 8 + 4);                    \
    } while (0)

#define L3ROW(r_, LR_) do {                                                \
        float p_ = w3v[0] / (1.f + __expf(-acc2[0][r_]))                   \
                 + w3v[1] / (1.f + __expf(-acc2[1][r_]))                   \
                 + w3v[2] / (1.f + __expf(-acc2[2][r_]));                  \
        p_ += __shfl_xor(p_, 1); p_ += __shfl_xor(p_, 2);                  \
        p_ += __shfl_xor(p_, 4); p_ += __shfl_xor(p_, 8);                  \
        int trow_ = tile_ * 16 + g4 * 4 + (r_);                            \
        LR_ = (trow_ < len) ? (p_ + b3v) * 0.125f                          \
            : (trow_ < 200 ? NEG_INF_F * 0.125f : -INFINITY);              \
    } while (0)

#define LOGITS(t_, K0_, K1_, K2_, K3_, LR0_, LR1_, LR2_, LR3_) do {        \
        const int tile_ = (t_);                                            \
        f32x4 acc[5];                                                      \
        _Pragma("unroll")                                                  \
        for (int nt = 0; nt < 5; ++nt)                                     \
            acc[nt] = (f32x4){hv[nt], hv[nt], hv[nt], hv[nt]};             \
        bf16x8 av0 = pack8(K0_, K1_);                                      \
        bf16x8 av1 = pack8(K2_, K3_);                                      \
        bf16x8 av2 = pack8m(K0_, K1_, q0, q0b);                            \
        bf16x8 av3 = pack8m(K2_, K3_, q1, q1b);                            \
        _Pragma("unroll")                                                  \
        for (int s = 0; s < 4; ++s) {                                      \
            bf16x8 a_ = (s == 0) ? av0 : (s == 1) ? av1                    \
                      : (s == 2) ? av2 : av3;                              \
            _Pragma("unroll")                                              \
            for (int nt = 0; nt < 5; ++nt) {                               \
                bf16x8 bfr = *(const bf16x8*)&w1s[((s * 5 + nt) * 64 + l) * 8]; \
                acc[nt] = __builtin_amdgcn_mfma_f32_16x16x32_bf16(         \
                    a_, bfr, acc[nt], 0, 0, 0);                            \
            }                                                              \
        }                                                                  \
        _Pragma("unroll")                                                  \
        for (int nt = 0; nt < 5; ++nt)                                     \
            _Pragma("unroll")                                              \
            for (int r = 0; r < 4; ++r) {                                  \
                float sg = 1.f / (1.f + __expf(-acc[nt][r]));              \
                myh1[(g4 * 4 + r) * 104 + nt * 16 + ln] = b16bits(sg);     \
            }                                                              \
        bf16x8 af0 = *(const bf16x8*)(myh1 + ln * 104 + g4 * 8);           \
        bf16x8 af1 = *(const bf16x8*)(myh1 + ln * 104 + 32 + g4 * 8);      \
        bf16x8 af2 = *(const bf16x8*)(myh1 + ln * 104 + 64 + g4 * 8);      \
        f32x4 acc2[3];                                                     \
        _Pragma("unroll")                                                  \
        for (int nt = 0; nt < 3; ++nt)                                     \
            acc2[nt] = (f32x4){b2v[nt], b2v[nt], b2v[nt], b2v[nt]};        \
        _Pragma("unroll")                                                  \
        for (int nt = 0; nt < 3; ++nt) {                                   \
            bf16x8 w0_ = *(const bf16x8*)(w2f + ((0 * 3 + nt) * 64 + l) * 8); \
            bf16x8 w1_ = *(const bf16x8*)(w2f + ((1 * 3 + nt) * 64 + l) * 8); \
            bf16x8 w2_ = *(const bf16x8*)(w2f + ((2 * 3 + nt) * 64 + l) * 8); \
            acc2[nt] = __builtin_amdgcn_mfma_f32_16x16x32_bf16(af0, w0_, acc2[nt], 0, 0, 0); \
            acc2[nt] = __builtin_amdgcn_mfma_f32_16x16x32_bf16(af1, w1_, acc2[nt], 0, 0, 0); \
            acc2[nt] = __builtin_amdgcn_mfma_f32_16x16x32_bf16(af2, w2_, acc2[nt], 0, 0, 0); \
        }                                                                  \
        L3ROW(0, LR0_); L3ROW(1, LR1_); L3ROW(2, LR2_); L3ROW(3, LR3_);    \
    } while (0)

    // Online update: rescale (only when tile max rises), accumulate s and o.
#define UPDATE(K0_, K1_, K2_, K3_, LR0_, LR1_, LR2_, LR3_) do {            \
        float mt_ = fmaxf(fmaxf(LR0_, LR1_), fmaxf(LR2_, LR3_));           \
        mt_ = fmaxf(mt_, __shfl_xor(mt_, 16));                             \
        mt_ = fmaxf(mt_, __shfl_xor(mt_, 32));                             \
        if (mt_ > m_run) {                                                 \
            float sc_ = __expf(m_run - mt_);                               \
            m_run = mt_;                                                   \
            s_part *= sc_;                                                 \
            o0.x *= sc_; o0.y *= sc_; o0.z *= sc_; o0.w *= sc_;            \
            o1.x *= sc_; o1.y *= sc_; o1.z *= sc_; o1.w *= sc_;            \
            o2.x *= sc_; o2.y *= sc_; o2.z *= sc_; o2.w *= sc_;            \
            o3.x *= sc_; o3.y *= sc_; o3.z *= sc_; o3.w *= sc_;            \
        }                                                                  \
        float p0_ = __expf(LR0_ - m_run), p1_ = __expf(LR1_ - m_run);      \
        float p2_ = __expf(LR2_ - m_run), p3_ = __expf(LR3_ - m_run);      \
        s_part += (p0_ + p1_) + (p2_ + p3_);                               \
        int src_ = (ln >> 2) << 4;                                         \
        float r0_ = __shfl(p0_, src_), r1_ = __shfl(p1_, src_);            \
        float r2_ = __shfl(p2_, src_), r3_ = __shfl(p3_, src_);            \
        int rr_ = ln & 3;                                                  \
        float pm_ = rr_ == 0 ? r0_ : rr_ == 1 ? r1_ : rr_ == 2 ? r2_ : r3_;\
        o0.x = fmaf(pm_, K0_.x, o0.x); o0.y = fmaf(pm_, K0_.y, o0.y);      \
        o0.z = fmaf(pm_, K0_.z, o0.z); o0.w = fmaf(pm_, K0_.w, o0.w);      \
        o1.x = fmaf(pm_, K1_.x, o1.x); o1.y = fmaf(pm_, K1_.y, o1.y);      \
        o1.z = fmaf(pm_, K1_.z, o1.z); o1.w = fmaf(pm_, K1_.w, o1.w);      \
        o2.x = fmaf(pm_, K2_.x, o2.x); o2.y = fmaf(pm_, K2_.y, o2.y);      \
        o2.z = fmaf(pm_, K2_.z, o2.z); o2.w = fmaf(pm_, K2_.w, o2.w);      \
        o3.x = fmaf(pm_, K3_.x, o3.x); o3.y = fmaf(pm_, K3_.y, o3.y);      \
        o3.z = fmaf(pm_, K3_.z, o3.z); o3.w = fmaf(pm_, K3_.w, o3.w);      \
    } while (0)

    float4 A0, A1, A2, A3, C0, C1, C2, C3;
    float la0, la1, la2, la3, lb0, lb1, lb2, lb3;
    LOADK(0, A0, A1, A2, A3);
    #pragma unroll 1
    for (int it = 0; it < 6; ++it) {
        const int t0 = 2 * it;
        LOADK(t0 + 1, C0, C1, C2, C3);
        LOGITS(t0, A0, A1, A2, A3, la0, la1, la2, la3);
        UPDATE(A0, A1, A2, A3, la0, la1, la2, la3);
        LOADK(t0 + 2, A0, A1, A2, A3);
        LOGITS(t0 + 1, C0, C1, C2, C3, lb0, lb1, lb2, lb3);
        UPDATE(C0, C1, C2, C3, lb0, lb1, lb2, lb3);
    }
    LOGITS(12, A0, A1, A2, A3, la0, la1, la2, la3);
    UPDATE(A0, A1, A2, A3, la0, la1, la2, la3);
#undef LOADK
#undef L3ROW
#undef LOGITS
#undef UPDATE

    // total sum: s_part identical within a g4 group -> reduce across groups
    float s_tot = s_part;
    s_tot += __shfl_xor(s_tot, 16);
    s_tot += __shfl_xor(s_tot, 32);
    const float inv = 1.f / s_tot;

    // reduce o over the 16 ln-lanes (butterfly), then stage 64 cols via LDS
#define RED16(x_) { x_ += __shfl_xor(x_, 1); x_ += __shfl_xor(x_, 2);      \
                    x_ += __shfl_xor(x_, 4); x_ += __shfl_xor(x_, 8); }
    RED16(o0.x) RED16(o0.y) RED16(o0.z) RED16(o0.w)
    RED16(o1.x) RED16(o1.y) RED16(o1.z) RED16(o1.w)
    RED16(o2.x) RED16(o2.y) RED16(o2.z) RED16(o2.w)
    RED16(o3.x) RED16(o3.y) RED16(o3.z) RED16(o3.w)
#undef RED16
    if (ln == 0) {
        float* od = olds[wid];
        od[g4 * 8 + 0] = o0.x; od[g4 * 8 + 1] = o0.y;
        od[g4 * 8 + 2] = o0.z; od[g4 * 8 + 3] = o0.w;
        od[g4 * 8 + 4] = o1.x; od[g4 * 8 + 5] = o1.y;
        od[g4 * 8 + 6] = o1.z; od[g4 * 8 + 7] = o1.w;
        od[32 + g4 * 8 + 0] = o2.x; od[32 + g4 * 8 + 1] = o2.y;
        od[32 + g4 * 8 + 2] = o2.z; od[32 + g4 * 8 + 3] = o2.w;
        od[32 + g4 * 8 + 4] = o3.x; od[32 + g4 * 8 + 5] = o3.y;
        od[32 + g4 * 8 + 6] = o3.z; od[32 + g4 * 8 + 7] = o3.w;
    }
    // same-wave LDS RAW: ds ops execute in order per wave; compiler waits.
    out[b * 64 + l] = olds[wid][l] * inv;
}

extern "C" void kernel_launch(void* const* d_in, const int* in_sizes, int n_in,
                              void* d_out, int out_size, void* d_ws, size_t ws_size,
                              hipStream_t stream) {
    const float* q    = (const float*)d_in[0];
    const float* keys = (const float*)d_in[1];
    const int*   kl   = (const int*)d_in[2];
    const float* W1   = (const float*)d_in[3];
    const float* b1   = (const float*)d_in[4];
    const float* W2   = (const float*)d_in[5];
    const float* b2   = (const float*)d_in[6];
    const float* W3   = (const float*)d_in[7];
    const float* b3   = (const float*)d_in[8];

    unsigned short* w1f = (unsigned short*)d_ws;            // 10240 bf16
    unsigned short* w2f = w1f + 10240;                      //  4608 bf16
    float* wqf   = (float*)((char*)d_ws + 32768);           //  5120 f32
    float* hinit = wqf + 5120;                              // 327680 f32

    fold_weights<<<(19968 + 255) / 256, 256, 0, stream>>>(W1, W2, w1f, w2f, wqf);
    hinit_kernel<<<(B_ * 80 + 255) / 256, 256, 0, stream>>>(q, wqf, b1, hinit);
    din_attn<<<B_ / 4, NT, 0, stream>>>(q, keys, kl, hinit, w1f, w2f, b2, W3, b3,
                                        (float*)d_out);
}

// Round 8
// 136.455 us; speedup vs baseline: 1.1172x; 1.1172x over previous
//
#include <hip/hip_runtime.h>
#include <math.h>

constexpr int B_ = 4096, T_ = 200, D_ = 64, NT = 256;
constexpr float NEG_INF_F = -4294967295.0f;  // float32(-2^32+1)

typedef __attribute__((ext_vector_type(8))) __bf16 bf16x8;
typedef __attribute__((ext_vector_type(4))) float f32x4;

__device__ __host__ inline unsigned short f2b_rne(float x) {
    unsigned u = __builtin_bit_cast(unsigned, x);
    u += 0x7FFF + ((u >> 16) & 1);
    return (unsigned short)(u >> 16);
}

__device__ inline unsigned short b16bits(float x) {
    return __builtin_bit_cast(unsigned short, (__bf16)x);
}

__device__ inline bf16x8 pack8(float4 lo, float4 hi) {
    bf16x8 r;
    r[0] = (__bf16)lo.x; r[1] = (__bf16)lo.y; r[2] = (__bf16)lo.z; r[3] = (__bf16)lo.w;
    r[4] = (__bf16)hi.x; r[5] = (__bf16)hi.y; r[6] = (__bf16)hi.z; r[7] = (__bf16)hi.w;
    return r;
}

__device__ inline bf16x8 pack8m(float4 lo, float4 hi, float4 ql, float4 qh) {
    bf16x8 r;
    r[0] = (__bf16)(lo.x * ql.x); r[1] = (__bf16)(lo.y * ql.y);
    r[2] = (__bf16)(lo.z * ql.z); r[3] = (__bf16)(lo.w * ql.w);
    r[4] = (__bf16)(hi.x * qh.x); r[5] = (__bf16)(hi.y * qh.y);
    r[6] = (__bf16)(hi.z * qh.z); r[7] = (__bf16)(hi.w * qh.w);
    return r;
}

// ---------------------------------------------------------------------------
// Fold weights into MFMA-fragment order (bf16). Same layouts as round 3.
// ---------------------------------------------------------------------------
__global__ void fold_weights(const float* __restrict__ W1,
                             const float* __restrict__ W2,
                             unsigned short* __restrict__ w1f,
                             unsigned short* __restrict__ w2f,
                             float* __restrict__ wqf) {
    int i = blockIdx.x * blockDim.x + threadIdx.x;
    if (i < 10240) {
        int j = i & 7, lane = (i >> 3) & 63, nt = (i >> 9) % 5, s = i / 2560;
        int k = s * 32 + (lane >> 4) * 8 + j;
        int n = nt * 16 + (lane & 15);
        float v = (k < 64) ? W1[(64 + k) * 80 + n] - W1[(128 + k) * 80 + n]
                           : W1[(192 + (k - 64)) * 80 + n];
        w1f[i] = f2b_rne(v);
    } else if (i < 14848) {
        int i2 = i - 10240;
        int j = i2 & 7, lane = (i2 >> 3) & 63, nt = (i2 >> 9) % 3, s = i2 / 1536;
        int k = s * 32 + (lane >> 4) * 8 + j;
        int n = nt * 16 + (lane & 15);
        float v = (k < 80 && n < 40) ? W2[k * 40 + n] : 0.f;
        w2f[i2] = f2b_rne(v);
    } else if (i < 19968) {
        int i3 = i - 14848;
        int n = i3 % 80, d = i3 / 80;
        wqf[i3] = W1[d * 80 + n] + W1[(128 + d) * 80 + n];
    }
}

__global__ __launch_bounds__(256)
void hinit_kernel(const float* __restrict__ q, const float* __restrict__ wqf,
                  const float* __restrict__ b1, float* __restrict__ hinit) {
    int i = blockIdx.x * blockDim.x + threadIdx.x;
    if (i >= B_ * 80) return;
    int b = i / 80, n = i - b * 80;
    const float* qr = q + b * 64;
    float acc = b1[n];
    #pragma unroll 8
    for (int d = 0; d < 64; ++d) acc = fmaf(qr[d], wqf[d * 80 + n], acc);
    hinit[i] = acc;
}

// ---------------------------------------------------------------------------
// Main kernel: round-6 structure (verified, 113us) with each batch row SPLIT
// across a wave pair: block = 4 waves = 2 rows; half 0 -> tiles 0..6,
// half 1 -> tiles 7..12. Halves the per-wave serial chain (round 6 was
// latency-bound: all pipes <52%). Round-7's online-softmax reverted (spilled:
// WRITE_SIZE 59MB). Grid = 2048 blocks.
// ---------------------------------------------------------------------------
__global__ __launch_bounds__(NT, 2)
void din_attn(const float* __restrict__ q, const float* __restrict__ keys,
              const int* __restrict__ klen, const float* __restrict__ hinit_g,
              const unsigned short* __restrict__ w1f,
              const unsigned short* __restrict__ w2f,
              const float* __restrict__ b2, const float* __restrict__ W3,
              const float* __restrict__ b3, float* __restrict__ out) {
    const int tid = threadIdx.x;
    const int l = tid & 63, wid = tid >> 6, g4 = l >> 4, ln = l & 15;
    const int pr = wid >> 1, hw = wid & 1;      // row-pair index, half index
    const int b = blockIdx.x * 2 + pr;

    alignas(16) __shared__ unsigned short w1s[10240];       // 20.5 KB W1 frags
    alignas(16) __shared__ unsigned short h1c[4][16 * 104]; // 13.3 KB wave-priv
    __shared__ float red[2][256];                           // 2 KB logits/attn
    __shared__ float opart[2][2][64];                       // 1 KB out partials

    #pragma unroll
    for (int j = 0; j < 5; ++j) {
        int idx = (j * 256 + tid) * 8;
        *(float4*)&w1s[idx] = *(const float4*)&w1f[idx];
    }
    float* myred = red[pr];
    unsigned short* myh1 = h1c[wid];
    if (l >= 8) myred[192 + l] = -INFINITY;   // pad rows 200..255 (same-value x2)
    #pragma unroll
    for (int r = 0; r < 4; ++r)
        myh1[(g4 * 4 + r) * 104 + 80 + ln] = 0;   // zero pad cols 80..95 once
    __syncthreads();   // w1s + red pads ready

    const int len = klen[b];
    const float b3v = b3[0];

    float hv[5], b2v[3], w3v[3];
    const float* hb = hinit_g + b * 80;
    #pragma unroll
    for (int nt = 0; nt < 5; ++nt) hv[nt] = hb[nt * 16 + ln];
    #pragma unroll
    for (int nt = 0; nt < 3; ++nt) {
        int idx = nt * 16 + ln;
        b2v[nt] = (idx < 40) ? b2[idx] : 0.f;
        w3v[nt] = (idx < 40) ? W3[idx] : 0.f;
    }
    const float* qb = q + b * 64;
    float4 q0  = *(const float4*)(qb + g4 * 8);
    float4 q0b = *(const float4*)(qb + g4 * 8 + 4);
    float4 q1  = *(const float4*)(qb + 32 + g4 * 8);
    float4 q1b = *(const float4*)(qb + 32 + g4 * 8 + 4);

    const float* kb = keys + (size_t)b * 200 * 64;

#define LOADK(tile_, B0_, B1_, B2_, B3_) do {                              \
        int t_ = (tile_) * 16 + ln;                                        \
        int tc_ = t_ < 200 ? t_ : 199;                                     \
        const float* row_ = kb + tc_ * 64;                                 \
        B0_ = *(const float4*)(row_ + g4 * 8);                             \
        B1_ = *(const float4*)(row_ + g4 * 8 + 4);                         \
        B2_ = *(const float4*)(row_ + 32 + g4 * 8);                        \
        B3_ = *(const float4*)(row_ + 32 + g4 * 8 + 4);                    \
    } while (0)

#define COMPUTE(tile_, K0_, K1_, K2_, K3_) do {                            \
        f32x4 acc[5];                                                      \
        _Pragma("unroll")                                                  \
        for (int nt = 0; nt < 5; ++nt)                                     \
            acc[nt] = (f32x4){hv[nt], hv[nt], hv[nt], hv[nt]};             \
        bf16x8 av0 = pack8(K0_, K1_);                                      \
        bf16x8 av1 = pack8(K2_, K3_);                                      \
        bf16x8 av2 = pack8m(K0_, K1_, q0, q0b);                            \
        bf16x8 av3 = pack8m(K2_, K3_, q1, q1b);                            \
        _Pragma("unroll")                                                  \
        for (int s = 0; s < 4; ++s) {                                      \
            bf16x8 a_ = (s == 0) ? av0 : (s == 1) ? av1                    \
                      : (s == 2) ? av2 : av3;                              \
            _Pragma("unroll")                                              \
            for (int nt = 0; nt < 5; ++nt) {                               \
                bf16x8 bfr = *(const bf16x8*)&w1s[((s * 5 + nt) * 64 + l) * 8]; \
                acc[nt] = __builtin_amdgcn_mfma_f32_16x16x32_bf16(         \
                    a_, bfr, acc[nt], 0, 0, 0);                            \
            }                                                              \
        }                                                                  \
        _Pragma("unroll")                                                  \
        for (int nt = 0; nt < 5; ++nt)                                     \
            _Pragma("unroll")                                              \
            for (int r = 0; r < 4; ++r) {                                  \
                float sg = 1.f / (1.f + __expf(-acc[nt][r]));              \
                myh1[(g4 * 4 + r) * 104 + nt * 16 + ln] = b16bits(sg);     \
            }                                                              \
        bf16x8 af0 = *(const bf16x8*)(myh1 + ln * 104 + g4 * 8);           \
        bf16x8 af1 = *(const bf16x8*)(myh1 + ln * 104 + 32 + g4 * 8);      \
        bf16x8 af2 = *(const bf16x8*)(myh1 + ln * 104 + 64 + g4 * 8);      \
        f32x4 acc2[3];                                                     \
        _Pragma("unroll")                                                  \
        for (int nt = 0; nt < 3; ++nt)                                     \
            acc2[nt] = (f32x4){b2v[nt], b2v[nt], b2v[nt], b2v[nt]};        \
        _Pragma("unroll")                                                  \
        for (int nt = 0; nt < 3; ++nt) {                                   \
            bf16x8 w0_ = *(const bf16x8*)(w2f + ((0 * 3 + nt) * 64 + l) * 8); \
            bf16x8 w1_ = *(const bf16x8*)(w2f + ((1 * 3 + nt) * 64 + l) * 8); \
            bf16x8 w2_ = *(const bf16x8*)(w2f + ((2 * 3 + nt) * 64 + l) * 8); \
            acc2[nt] = __builtin_amdgcn_mfma_f32_16x16x32_bf16(af0, w0_, acc2[nt], 0, 0, 0); \
            acc2[nt] = __builtin_amdgcn_mfma_f32_16x16x32_bf16(af1, w1_, acc2[nt], 0, 0, 0); \
            acc2[nt] = __builtin_amdgcn_mfma_f32_16x16x32_bf16(af2, w2_, acc2[nt], 0, 0, 0); \
        }                                                                  \
        _Pragma("unroll")                                                  \
        for (int r = 0; r < 4; ++r) {                                      \
            float p = w3v[0] / (1.f + __expf(-acc2[0][r]))                 \
                    + w3v[1] / (1.f + __expf(-acc2[1][r]))                 \
                    + w3v[2] / (1.f + __expf(-acc2[2][r]));                \
            p += __shfl_xor(p, 1); p += __shfl_xor(p, 2);                  \
            p += __shfl_xor(p, 4); p += __shfl_xor(p, 8);                  \
            if (ln == 0) {                                                 \
                int trow = (tile_) * 16 + g4 * 4 + r;                      \
                if (trow < 200)                                            \
                    myred[trow] = (trow < len) ? (p + b3v) * 0.125f        \
                                               : NEG_INF_F * 0.125f;       \
            }                                                              \
        }                                                                  \
    } while (0)

    // half 0: tiles 0..6 (7); half 1: tiles 7..12 (6). Runtime ping-pong loop.
    {
        const int tb = hw ? 7 : 0;
        const int te = hw ? 13 : 7;
        float4 A0, A1, A2, A3, C0, C1, C2, C3;
        LOADK(tb, A0, A1, A2, A3);
        int it = tb;
        #pragma unroll 1
        while (it + 2 <= te) {
            LOADK(it + 1, C0, C1, C2, C3);
            COMPUTE(it, A0, A1, A2, A3);
            if (it + 2 < te) { LOADK(it + 2, A0, A1, A2, A3); }
            COMPUTE(it + 1, C0, C1, C2, C3);
            it += 2;
        }
        if (it < te) COMPUTE(it, A0, A1, A2, A3);   // odd tail (half 0: tile 6)
    }
#undef LOADK
#undef COMPUTE
    __syncthreads();   // logits of both halves in red[pr]

    // ------------- softmax (each wave of the pair, redundant) -------------
    float v0 = myred[l], v1 = myred[64 + l], v2 = myred[128 + l], v3 = myred[192 + l];
    float m = fmaxf(fmaxf(v0, v1), fmaxf(v2, v3));
    #pragma unroll
    for (int off = 32; off; off >>= 1) m = fmaxf(m, __shfl_xor(m, off));
    float e0 = __expf(v0 - m), e1 = __expf(v1 - m);
    float e2 = __expf(v2 - m), e3 = __expf(v3 - m);
    float s = (e0 + e1) + (e2 + e3);
    #pragma unroll
    for (int off = 32; off; off >>= 1) s += __shfl_xor(s, off);
    const float invs = 1.f / s;
    // same-value write-back by both waves of the pair (bitwise identical)
    myred[l] = e0 * invs; myred[64 + l] = e1 * invs;
    myred[128 + l] = e2 * invs; myred[192 + l] = e3 * invs;
    // own-wave wrote all 256 -> own reads safe without a barrier

    // ------------- output: each wave does its 100-t half -------------
    {
        const int t0 = hw * 100;
        float a0 = 0.f, a1 = 0.f, a2 = 0.f, a3 = 0.f;
        #pragma unroll 2
        for (int t = t0; t < t0 + 100; t += 4) {
            a0 = fmaf(myred[t],     kb[(t)     * 64 + l], a0);
            a1 = fmaf(myred[t + 1], kb[(t + 1) * 64 + l], a1);
            a2 = fmaf(myred[t + 2], kb[(t + 2) * 64 + l], a2);
            a3 = fmaf(myred[t + 3], kb[(t + 3) * 64 + l], a3);
        }
        opart[pr][hw][l] = (a0 + a1) + (a2 + a3);
    }
    __syncthreads();
    if (hw == 0)
        out[b * 64 + l] = opart[pr][0][l] + opart[pr][1][l];
}

extern "C" void kernel_launch(void* const* d_in, const int* in_sizes, int n_in,
                              void* d_out, int out_size, void* d_ws, size_t ws_size,
                              hipStream_t stream) {
    const float* q    = (const float*)d_in[0];
    const float* keys = (const float*)d_in[1];
    const int*   kl   = (const int*)d_in[2];
    const float* W1   = (const float*)d_in[3];
    const float* b1   = (const float*)d_in[4];
    const float* W2   = (const float*)d_in[5];
    const float* b2   = (const float*)d_in[6];
    const float* W3   = (const float*)d_in[7];
    const float* b3   = (const float*)d_in[8];

    unsigned short* w1f = (unsigned short*)d_ws;            // 10240 bf16
    unsigned short* w2f = w1f + 10240;                      //  4608 bf16
    float* wqf   = (float*)((char*)d_ws + 32768);           //  5120 f32
    float* hinit = wqf + 5120;                              // 327680 f32

    fold_weights<<<(19968 + 255) / 256, 256, 0, stream>>>(W1, W2, w1f, w2f, wqf);
    hinit_kernel<<<(B_ * 80 + 255) / 256, 256, 0, stream>>>(q, wqf, b1, hinit);
    din_attn<<<B_ / 2, NT, 0, stream>>>(q, keys, kl, hinit, w1f, w2f, b2, W3, b3,
                                        (float*)d_out);
}

// Round 9
// 108.543 us; speedup vs baseline: 1.4045x; 1.2572x over previous
//
#include <hip/hip_runtime.h>
#include <math.h>

constexpr int B_ = 4096, T_ = 200, D_ = 64, NT = 256;
constexpr float NEG_INF_F = -4294967295.0f;  // float32(-2^32+1)

typedef __attribute__((ext_vector_type(8))) __bf16 bf16x8;
typedef __attribute__((ext_vector_type(4))) float f32x4;

__device__ __host__ inline unsigned short f2b_rne(float x) {
    unsigned u = __builtin_bit_cast(unsigned, x);
    u += 0x7FFF + ((u >> 16) & 1);
    return (unsigned short)(u >> 16);
}

__device__ inline unsigned short b16bits(float x) {
    return __builtin_bit_cast(unsigned short, (__bf16)x);
}

__device__ inline bf16x8 pack8(float4 lo, float4 hi) {
    bf16x8 r;
    r[0] = (__bf16)lo.x; r[1] = (__bf16)lo.y; r[2] = (__bf16)lo.z; r[3] = (__bf16)lo.w;
    r[4] = (__bf16)hi.x; r[5] = (__bf16)hi.y; r[6] = (__bf16)hi.z; r[7] = (__bf16)hi.w;
    return r;
}

// ---------------------------------------------------------------------------
// Fold weights into MFMA-fragment order (bf16). Same layouts as round 3.
// w1f[s=0..3][nt=0..4][lane][j]: s<2 -> Wk (K rows 0..63), s>=2 -> Wqk.
// ---------------------------------------------------------------------------
__global__ void fold_weights(const float* __restrict__ W1,
                             const float* __restrict__ W2,
                             unsigned short* __restrict__ w1f,
                             unsigned short* __restrict__ w2f,
                             float* __restrict__ wqf) {
    int i = blockIdx.x * blockDim.x + threadIdx.x;
    if (i < 10240) {
        int j = i & 7, lane = (i >> 3) & 63, nt = (i >> 9) % 5, s = i / 2560;
        int k = s * 32 + (lane >> 4) * 8 + j;
        int n = nt * 16 + (lane & 15);
        float v = (k < 64) ? W1[(64 + k) * 80 + n] - W1[(128 + k) * 80 + n]
                           : W1[(192 + (k - 64)) * 80 + n];
        w1f[i] = f2b_rne(v);
    } else if (i < 14848) {
        int i2 = i - 10240;
        int j = i2 & 7, lane = (i2 >> 3) & 63, nt = (i2 >> 9) % 3, s = i2 / 1536;
        int k = s * 32 + (lane >> 4) * 8 + j;
        int n = nt * 16 + (lane & 15);
        float v = (k < 80 && n < 40) ? W2[k * 40 + n] : 0.f;
        w2f[i2] = f2b_rne(v);
    } else if (i < 19968) {
        int i3 = i - 14848;
        int n = i3 % 80, d = i3 / 80;
        wqf[i3] = W1[d * 80 + n] + W1[(128 + d) * 80 + n];
    }
}

__global__ __launch_bounds__(256)
void hinit_kernel(const float* __restrict__ q, const float* __restrict__ wqf,
                  const float* __restrict__ b1, float* __restrict__ hinit) {
    int i = blockIdx.x * blockDim.x + threadIdx.x;
    if (i >= B_ * 80) return;
    int b = i / 80, n = i - b * 80;
    const float* qr = q + b * 64;
    float acc = b1[n];
    #pragma unroll 8
    for (int d = 0; d < 64; ++d) acc = fmaf(qr[d], wqf[d * 80 + n], acc);
    hinit[i] = acc;
}

// ---------------------------------------------------------------------------
// Main kernel (round-6 structure, barrier-FREE): one wave = one batch row,
// 4 rows/block. Per-row weight fold W_eff = Wk + q (.) Wqk is built ONCE into
// 10 register-resident B-fragments -> layer-1 K halves (128->64): 10 MFMA
// per tile, zero LDS traffic in layer 1, no w1s stage, no block barrier.
// ---------------------------------------------------------------------------
__global__ __launch_bounds__(NT, 2)
void din_attn(const float* __restrict__ q, const float* __restrict__ keys,
              const int* __restrict__ klen, const float* __restrict__ hinit_g,
              const unsigned short* __restrict__ w1f,
              const unsigned short* __restrict__ w2f,
              const float* __restrict__ b2, const float* __restrict__ W3,
              const float* __restrict__ b3, float* __restrict__ out) {
    const int tid = threadIdx.x;
    const int l = tid & 63, wid = tid >> 6, g4 = l >> 4, ln = l & 15;
    const int b = blockIdx.x * 4 + wid;

    alignas(16) __shared__ unsigned short h1c[4][16 * 104]; // 13.3 KB wave-priv
    __shared__ float red[4][256];                           // 4 KB logits/attn

    float* myred = red[wid];
    unsigned short* myh1 = h1c[wid];
    if (l >= 8) myred[192 + l] = -INFINITY;   // pad rows 200..255 (own-wave)
    #pragma unroll
    for (int r = 0; r < 4; ++r)
        myh1[(g4 * 4 + r) * 104 + 80 + ln] = 0;   // zero pad cols 80..95 once

    const int len = klen[b];
    const float b3v = b3[0];

    float hv[5], b2v[3], w3v[3];
    const float* hb = hinit_g + b * 80;
    #pragma unroll
    for (int nt = 0; nt < 5; ++nt) hv[nt] = hb[nt * 16 + ln];
    #pragma unroll
    for (int nt = 0; nt < 3; ++nt) {
        int idx = nt * 16 + ln;
        b2v[nt] = (idx < 40) ? b2[idx] : 0.f;
        w3v[nt] = (idx < 40) ? W3[idx] : 0.f;
    }

    // q fragment values for this row (lane l holds q[s*32 + g4*8 + j])
    const float* qb = q + b * 64;
    float4 q0  = *(const float4*)(qb + g4 * 8);
    float4 q0b = *(const float4*)(qb + g4 * 8 + 4);
    float4 q1  = *(const float4*)(qb + 32 + g4 * 8);
    float4 q1b = *(const float4*)(qb + 32 + g4 * 8 + 4);

    // ---- build W_eff = Wk + q (.) Wqk as 10 register B-frags (once/row) ----
    bf16x8 wf_[2][5];
    #pragma unroll
    for (int s = 0; s < 2; ++s) {
        float qa0 = (s == 0) ? q0.x  : q1.x,  qa1 = (s == 0) ? q0.y  : q1.y;
        float qa2 = (s == 0) ? q0.z  : q1.z,  qa3 = (s == 0) ? q0.w  : q1.w;
        float qb0 = (s == 0) ? q0b.x : q1b.x, qb1 = (s == 0) ? q0b.y : q1b.y;
        float qb2 = (s == 0) ? q0b.z : q1b.z, qb3 = (s == 0) ? q0b.w : q1b.w;
        #pragma unroll
        for (int nt = 0; nt < 5; ++nt) {
            bf16x8 wk = *(const bf16x8*)&w1f[((s * 5 + nt) * 64 + l) * 8];
            bf16x8 wq = *(const bf16x8*)&w1f[(((s + 2) * 5 + nt) * 64 + l) * 8];
            bf16x8 r;
            r[0] = (__bf16)fmaf(qa0, (float)wq[0], (float)wk[0]);
            r[1] = (__bf16)fmaf(qa1, (float)wq[1], (float)wk[1]);
            r[2] = (__bf16)fmaf(qa2, (float)wq[2], (float)wk[2]);
            r[3] = (__bf16)fmaf(qa3, (float)wq[3], (float)wk[3]);
            r[4] = (__bf16)fmaf(qb0, (float)wq[4], (float)wk[4]);
            r[5] = (__bf16)fmaf(qb1, (float)wq[5], (float)wk[5]);
            r[6] = (__bf16)fmaf(qb2, (float)wq[6], (float)wk[6]);
            r[7] = (__bf16)fmaf(qb3, (float)wq[7], (float)wk[7]);
            wf_[s][nt] = r;
        }
    }

    const float* kb = keys + (size_t)b * 200 * 64;

#define LOADK(tile_, B0_, B1_, B2_, B3_) do {                              \
        int t_ = (tile_) * 16 + ln;                                        \
        int tc_ = t_ < 200 ? t_ : 199;                                     \
        const float* row_ = kb + tc_ * 64;                                 \
        B0_ = *(const float4*)(row_ + g4 * 8);                             \
        B1_ = *(const float4*)(row_ + g4 * 8 + 4);                         \
        B2_ = *(const float4*)(row_ + 32 + g4 * 8);                        \
        B3_ = *(const float4*)(row_ + 32 + g4 * 8 + 4);                    \
    } while (0)

#define COMPUTE(tile_, K0_, K1_, K2_, K3_) do {                            \
        f32x4 acc[5];                                                      \
        _Pragma("unroll")                                                  \
        for (int nt = 0; nt < 5; ++nt)                                     \
            acc[nt] = (f32x4){hv[nt], hv[nt], hv[nt], hv[nt]};             \
        bf16x8 av0 = pack8(K0_, K1_);                                      \
        bf16x8 av1 = pack8(K2_, K3_);                                      \
        _Pragma("unroll")                                                  \
        for (int nt = 0; nt < 5; ++nt) {                                   \
            acc[nt] = __builtin_amdgcn_mfma_f32_16x16x32_bf16(             \
                av0, wf_[0][nt], acc[nt], 0, 0, 0);                        \
            acc[nt] = __builtin_amdgcn_mfma_f32_16x16x32_bf16(             \
                av1, wf_[1][nt], acc[nt], 0, 0, 0);                        \
        }                                                                  \
        _Pragma("unroll")                                                  \
        for (int nt = 0; nt < 5; ++nt)                                     \
            _Pragma("unroll")                                              \
            for (int r = 0; r < 4; ++r) {                                  \
                float sg = 1.f / (1.f + __expf(-acc[nt][r]));              \
                myh1[(g4 * 4 + r) * 104 + nt * 16 + ln] = b16bits(sg);     \
            }                                                              \
        bf16x8 af0 = *(const bf16x8*)(myh1 + ln * 104 + g4 * 8);           \
        bf16x8 af1 = *(const bf16x8*)(myh1 + ln * 104 + 32 + g4 * 8);      \
        bf16x8 af2 = *(const bf16x8*)(myh1 + ln * 104 + 64 + g4 * 8);      \
        f32x4 acc2[3];                                                     \
        _Pragma("unroll")                                                  \
        for (int nt = 0; nt < 3; ++nt)                                     \
            acc2[nt] = (f32x4){b2v[nt], b2v[nt], b2v[nt], b2v[nt]};        \
        _Pragma("unroll")                                                  \
        for (int nt = 0; nt < 3; ++nt) {                                   \
            bf16x8 w0_ = *(const bf16x8*)(w2f + ((0 * 3 + nt) * 64 + l) * 8); \
            bf16x8 w1_ = *(const bf16x8*)(w2f + ((1 * 3 + nt) * 64 + l) * 8); \
            bf16x8 w2_ = *(const bf16x8*)(w2f + ((2 * 3 + nt) * 64 + l) * 8); \
            acc2[nt] = __builtin_amdgcn_mfma_f32_16x16x32_bf16(af0, w0_, acc2[nt], 0, 0, 0); \
            acc2[nt] = __builtin_amdgcn_mfma_f32_16x16x32_bf16(af1, w1_, acc2[nt], 0, 0, 0); \
            acc2[nt] = __builtin_amdgcn_mfma_f32_16x16x32_bf16(af2, w2_, acc2[nt], 0, 0, 0); \
        }                                                                  \
        _Pragma("unroll")                                                  \
        for (int r = 0; r < 4; ++r) {                                      \
            float p = w3v[0] / (1.f + __expf(-acc2[0][r]))                 \
                    + w3v[1] / (1.f + __expf(-acc2[1][r]))                 \
                    + w3v[2] / (1.f + __expf(-acc2[2][r]));                \
            p += __shfl_xor(p, 1); p += __shfl_xor(p, 2);                  \
            p += __shfl_xor(p, 4); p += __shfl_xor(p, 8);                  \
            if (ln == 0) {                                                 \
                int trow = (tile_) * 16 + g4 * 4 + r;                      \
                if (trow < 200)                                            \
                    myred[trow] = (trow < len) ? (p + b3v) * 0.125f        \
                                               : NEG_INF_F * 0.125f;       \
            }                                                              \
        }                                                                  \
    } while (0)

    // 13 tiles, 2-deep ping-pong prefetch, runtime loop (keeps VGPR in check)
    float4 A0, A1, A2, A3, C0, C1, C2, C3;
    LOADK(0, A0, A1, A2, A3);
    #pragma unroll 1
    for (int it = 0; it < 6; ++it) {
        int t0 = 2 * it;
        LOADK(t0 + 1, C0, C1, C2, C3);
        COMPUTE(t0, A0, A1, A2, A3);
        LOADK(t0 + 2, A0, A1, A2, A3);
        COMPUTE(t0 + 1, C0, C1, C2, C3);
    }
    COMPUTE(12, A0, A1, A2, A3);
#undef LOADK
#undef COMPUTE

    // ---------------- wave-local softmax over myred[0..255] ----------------
    float v0 = myred[l], v1 = myred[64 + l], v2 = myred[128 + l], v3 = myred[192 + l];
    float m = fmaxf(fmaxf(v0, v1), fmaxf(v2, v3));
    #pragma unroll
    for (int off = 32; off; off >>= 1) m = fmaxf(m, __shfl_xor(m, off));
    float e0 = __expf(v0 - m), e1 = __expf(v1 - m);
    float e2 = __expf(v2 - m), e3 = __expf(v3 - m);
    float s = (e0 + e1) + (e2 + e3);
    #pragma unroll
    for (int off = 32; off; off >>= 1) s += __shfl_xor(s, off);
    myred[l] = e0 / s; myred[64 + l] = e1 / s;
    myred[128 + l] = e2 / s; myred[192 + l] = e3 / s;

    // ---------------- output: out[b][l] = sum_t attn[t]*keys[b][t][l] ------
    float a0 = 0.f, a1 = 0.f, a2 = 0.f, a3 = 0.f;
    #pragma unroll 2
    for (int t = 0; t < 200; t += 4) {
        a0 = fmaf(myred[t],     kb[(t)     * 64 + l], a0);
        a1 = fmaf(myred[t + 1], kb[(t + 1) * 64 + l], a1);
        a2 = fmaf(myred[t + 2], kb[(t + 2) * 64 + l], a2);
        a3 = fmaf(myred[t + 3], kb[(t + 3) * 64 + l], a3);
    }
    out[b * 64 + l] = (a0 + a1) + (a2 + a3);
}

extern "C" void kernel_launch(void* const* d_in, const int* in_sizes, int n_in,
                              void* d_out, int out_size, void* d_ws, size_t ws_size,
                              hipStream_t stream) {
    const float* q    = (const float*)d_in[0];
    const float* keys = (const float*)d_in[1];
    const int*   kl   = (const int*)d_in[2];
    const float* W1   = (const float*)d_in[3];
    const float* b1   = (const float*)d_in[4];
    const float* W2   = (const float*)d_in[5];
    const float* b2   = (const float*)d_in[6];
    const float* W3   = (const float*)d_in[7];
    const float* b3   = (const float*)d_in[8];

    unsigned short* w1f = (unsigned short*)d_ws;            // 10240 bf16
    unsigned short* w2f = w1f + 10240;                      //  4608 bf16
    float* wqf   = (float*)((char*)d_ws + 32768);           //  5120 f32
    float* hinit = wqf + 5120;                              // 327680 f32

    fold_weights<<<(19968 + 255) / 256, 256, 0, stream>>>(W1, W2, w1f, w2f, wqf);
    hinit_kernel<<<(B_ * 80 + 255) / 256, 256, 0, stream>>>(q, wqf, b1, hinit);
    din_attn<<<B_ / 4, NT, 0, stream>>>(q, keys, kl, hinit, w1f, w2f, b2, W3, b3,
                                        (float*)d_out);
}

// Round 10
// 87.601 us; speedup vs baseline: 1.7403x; 1.2391x over previous
//
#include <hip/hip_runtime.h>
#include <math.h>

constexpr int B_ = 4096, T_ = 200, D_ = 64, NT = 256;
constexpr float NEG_INF_F = -4294967295.0f;  // float32(-2^32+1)

typedef __attribute__((ext_vector_type(8))) __bf16 bf16x8;
typedef __attribute__((ext_vector_type(4))) float f32x4;

__device__ __host__ inline unsigned short f2b_rne(float x) {
    unsigned u = __builtin_bit_cast(unsigned, x);
    u += 0x7FFF + ((u >> 16) & 1);
    return (unsigned short)(u >> 16);
}

__device__ inline unsigned short b16bits(float x) {
    return __builtin_bit_cast(unsigned short, (__bf16)x);
}

__device__ inline float frcp(float x) { return __builtin_amdgcn_rcpf(x); }

__device__ inline bf16x8 pack8(float4 lo, float4 hi) {
    bf16x8 r;
    r[0] = (__bf16)lo.x; r[1] = (__bf16)lo.y; r[2] = (__bf16)lo.z; r[3] = (__bf16)lo.w;
    r[4] = (__bf16)hi.x; r[5] = (__bf16)hi.y; r[6] = (__bf16)hi.z; r[7] = (__bf16)hi.w;
    return r;
}

// ---------------------------------------------------------------------------
// Fold weights into MFMA-fragment order (bf16). Same layouts as round 3.
// ---------------------------------------------------------------------------
__global__ void fold_weights(const float* __restrict__ W1,
                             const float* __restrict__ W2,
                             unsigned short* __restrict__ w1f,
                             unsigned short* __restrict__ w2f,
                             float* __restrict__ wqf) {
    int i = blockIdx.x * blockDim.x + threadIdx.x;
    if (i < 10240) {
        int j = i & 7, lane = (i >> 3) & 63, nt = (i >> 9) % 5, s = i / 2560;
        int k = s * 32 + (lane >> 4) * 8 + j;
        int n = nt * 16 + (lane & 15);
        float v = (k < 64) ? W1[(64 + k) * 80 + n] - W1[(128 + k) * 80 + n]
                           : W1[(192 + (k - 64)) * 80 + n];
        w1f[i] = f2b_rne(v);
    } else if (i < 14848) {
        int i2 = i - 10240;
        int j = i2 & 7, lane = (i2 >> 3) & 63, nt = (i2 >> 9) % 3, s = i2 / 1536;
        int k = s * 32 + (lane >> 4) * 8 + j;
        int n = nt * 16 + (lane & 15);
        float v = (k < 80 && n < 40) ? W2[k * 40 + n] : 0.f;
        w2f[i2] = f2b_rne(v);
    } else if (i < 19968) {
        int i3 = i - 14848;
        int n = i3 % 80, d = i3 / 80;
        wqf[i3] = W1[d * 80 + n] + W1[(128 + d) * 80 + n];
    }
}

__global__ __launch_bounds__(256)
void hinit_kernel(const float* __restrict__ q, const float* __restrict__ wqf,
                  const float* __restrict__ b1, float* __restrict__ hinit) {
    int i = blockIdx.x * blockDim.x + threadIdx.x;
    if (i >= B_ * 80) return;
    int b = i / 80, n = i - b * 80;
    const float* qr = q + b * 64;
    float acc = b1[n];
    #pragma unroll 8
    for (int d = 0; d < 64; ++d) acc = fmaf(qr[d], wqf[d * 80 + n], acc);
    hinit[i] = acc;
}

// ---------------------------------------------------------------------------
// Main kernel (round-9 structure + 2 changes):
//  (a) fast v_rcp_f32 for all sigmoid/div (precise f32 div was ~15 ops each),
//  (b) 2-tile software pipeline with double-buffered h1 chunk: h1-read(i)
//      issues early, L1(i+1)+sigmoid fills the LDS latency, L2(i) consumes.
// One wave = one batch row, barrier-free; W_eff in 10 register B-frags.
// ---------------------------------------------------------------------------
__global__ __launch_bounds__(NT, 2)
void din_attn(const float* __restrict__ q, const float* __restrict__ keys,
              const int* __restrict__ klen, const float* __restrict__ hinit_g,
              const unsigned short* __restrict__ w1f,
              const unsigned short* __restrict__ w2f,
              const float* __restrict__ b2, const float* __restrict__ W3,
              const float* __restrict__ b3, float* __restrict__ out) {
    const int tid = threadIdx.x;
    const int l = tid & 63, wid = tid >> 6, g4 = l >> 4, ln = l & 15;
    const int b = blockIdx.x * 4 + wid;

    alignas(16) __shared__ unsigned short h1c[4][2][16 * 104]; // 26.6 KB dbuf
    __shared__ float red[4][256];                              // 4 KB

    float* myred = red[wid];
    unsigned short* buf0 = h1c[wid][0];
    unsigned short* buf1 = h1c[wid][1];
    if (l >= 8) myred[192 + l] = -INFINITY;   // pad rows 200..255 (own-wave)
    #pragma unroll
    for (int r = 0; r < 4; ++r) {             // zero pad cols 80..95 once
        buf0[(g4 * 4 + r) * 104 + 80 + ln] = 0;
        buf1[(g4 * 4 + r) * 104 + 80 + ln] = 0;
    }

    const int len = klen[b];
    const float b3v = b3[0];

    float hv[5], b2v[3], w3v[3];
    const float* hb = hinit_g + b * 80;
    #pragma unroll
    for (int nt = 0; nt < 5; ++nt) hv[nt] = hb[nt * 16 + ln];
    #pragma unroll
    for (int nt = 0; nt < 3; ++nt) {
        int idx = nt * 16 + ln;
        b2v[nt] = (idx < 40) ? b2[idx] : 0.f;
        w3v[nt] = (idx < 40) ? W3[idx] : 0.f;
    }

    const float* qb = q + b * 64;
    float4 q0  = *(const float4*)(qb + g4 * 8);
    float4 q0b = *(const float4*)(qb + g4 * 8 + 4);
    float4 q1  = *(const float4*)(qb + 32 + g4 * 8);
    float4 q1b = *(const float4*)(qb + 32 + g4 * 8 + 4);

    // ---- build W_eff = Wk + q (.) Wqk as 10 register B-frags (once/row) ----
    bf16x8 wf_[2][5];
    #pragma unroll
    for (int s = 0; s < 2; ++s) {
        float qa0 = (s == 0) ? q0.x  : q1.x,  qa1 = (s == 0) ? q0.y  : q1.y;
        float qa2 = (s == 0) ? q0.z  : q1.z,  qa3 = (s == 0) ? q0.w  : q1.w;
        float qb0 = (s == 0) ? q0b.x : q1b.x, qb1 = (s == 0) ? q0b.y : q1b.y;
        float qb2 = (s == 0) ? q0b.z : q1b.z, qb3 = (s == 0) ? q0b.w : q1b.w;
        #pragma unroll
        for (int nt = 0; nt < 5; ++nt) {
            bf16x8 wk = *(const bf16x8*)&w1f[((s * 5 + nt) * 64 + l) * 8];
            bf16x8 wq = *(const bf16x8*)&w1f[(((s + 2) * 5 + nt) * 64 + l) * 8];
            bf16x8 r;
            r[0] = (__bf16)fmaf(qa0, (float)wq[0], (float)wk[0]);
            r[1] = (__bf16)fmaf(qa1, (float)wq[1], (float)wk[1]);
            r[2] = (__bf16)fmaf(qa2, (float)wq[2], (float)wk[2]);
            r[3] = (__bf16)fmaf(qa3, (float)wq[3], (float)wk[3]);
            r[4] = (__bf16)fmaf(qb0, (float)wq[4], (float)wk[4]);
            r[5] = (__bf16)fmaf(qb1, (float)wq[5], (float)wk[5]);
            r[6] = (__bf16)fmaf(qb2, (float)wq[6], (float)wk[6]);
            r[7] = (__bf16)fmaf(qb3, (float)wq[7], (float)wk[7]);
            wf_[s][nt] = r;
        }
    }

    const float* kb = keys + (size_t)b * 200 * 64;

#define LOADK(tile_, B0_, B1_, B2_, B3_) do {                              \
        int t_ = (tile_) * 16 + ln;                                        \
        int tc_ = t_ < 200 ? t_ : 199;                                     \
        const float* row_ = kb + tc_ * 64;                                 \
        B0_ = *(const float4*)(row_ + g4 * 8);                             \
        B1_ = *(const float4*)(row_ + g4 * 8 + 4);                         \
        B2_ = *(const float4*)(row_ + 32 + g4 * 8);                        \
        B3_ = *(const float4*)(row_ + 32 + g4 * 8 + 4);                    \
    } while (0)

#define L1SIG(K0_, K1_, K2_, K3_, DST_) do {                               \
        f32x4 acc[5];                                                      \
        _Pragma("unroll")                                                  \
        for (int nt = 0; nt < 5; ++nt)                                     \
            acc[nt] = (f32x4){hv[nt], hv[nt], hv[nt], hv[nt]};             \
        bf16x8 av0 = pack8(K0_, K1_);                                      \
        bf16x8 av1 = pack8(K2_, K3_);                                      \
        _Pragma("unroll")                                                  \
        for (int nt = 0; nt < 5; ++nt) {                                   \
            acc[nt] = __builtin_amdgcn_mfma_f32_16x16x32_bf16(             \
                av0, wf_[0][nt], acc[nt], 0, 0, 0);                        \
            acc[nt] = __builtin_amdgcn_mfma_f32_16x16x32_bf16(             \
                av1, wf_[1][nt], acc[nt], 0, 0, 0);                        \
        }                                                                  \
        _Pragma("unroll")                                                  \
        for (int nt = 0; nt < 5; ++nt)                                     \
            _Pragma("unroll")                                              \
            for (int r = 0; r < 4; ++r) {                                  \
                float sg = frcp(1.f + __expf(-acc[nt][r]));                \
                (DST_)[(g4 * 4 + r) * 104 + nt * 16 + ln] = b16bits(sg);   \
            }                                                              \
    } while (0)

#define AFREAD(SRC_) do {                                                  \
        af0 = *(const bf16x8*)((SRC_) + ln * 104 + g4 * 8);                \
        af1 = *(const bf16x8*)((SRC_) + ln * 104 + 32 + g4 * 8);           \
        af2 = *(const bf16x8*)((SRC_) + ln * 104 + 64 + g4 * 8);           \
    } while (0)

#define L2L3(tile_) do {                                                   \
        f32x4 acc2[3];                                                     \
        _Pragma("unroll")                                                  \
        for (int nt = 0; nt < 3; ++nt)                                     \
            acc2[nt] = (f32x4){b2v[nt], b2v[nt], b2v[nt], b2v[nt]};        \
        _Pragma("unroll")                                                  \
        for (int nt = 0; nt < 3; ++nt) {                                   \
            bf16x8 w0_ = *(const bf16x8*)(w2f + ((0 * 3 + nt) * 64 + l) * 8); \
            bf16x8 w1_ = *(const bf16x8*)(w2f + ((1 * 3 + nt) * 64 + l) * 8); \
            bf16x8 w2_ = *(const bf16x8*)(w2f + ((2 * 3 + nt) * 64 + l) * 8); \
            acc2[nt] = __builtin_amdgcn_mfma_f32_16x16x32_bf16(af0, w0_, acc2[nt], 0, 0, 0); \
            acc2[nt] = __builtin_amdgcn_mfma_f32_16x16x32_bf16(af1, w1_, acc2[nt], 0, 0, 0); \
            acc2[nt] = __builtin_amdgcn_mfma_f32_16x16x32_bf16(af2, w2_, acc2[nt], 0, 0, 0); \
        }                                                                  \
        _Pragma("unroll")                                                  \
        for (int r = 0; r < 4; ++r) {                                      \
            float p = w3v[0] * frcp(1.f + __expf(-acc2[0][r]))             \
                    + w3v[1] * frcp(1.f + __expf(-acc2[1][r]))             \
                    + w3v[2] * frcp(1.f + __expf(-acc2[2][r]));            \
            p += __shfl_xor(p, 1); p += __shfl_xor(p, 2);                  \
            p += __shfl_xor(p, 4); p += __shfl_xor(p, 8);                  \
            if (ln == 0) {                                                 \
                int trow = (tile_) * 16 + g4 * 4 + r;                      \
                if (trow < 200)                                            \
                    myred[trow] = (trow < len) ? (p + b3v) * 0.125f        \
                                               : NEG_INF_F * 0.125f;       \
            }                                                              \
        }                                                                  \
    } while (0)

    // ---- 2-tile pipeline: L1(i+1) overlaps the LDS round-trip of L2(i) ----
    float4 A0, A1, A2, A3, C0, C1, C2, C3;
    bf16x8 af0, af1, af2;
    LOADK(0, A0, A1, A2, A3);
    L1SIG(A0, A1, A2, A3, buf0);
    LOADK(1, C0, C1, C2, C3);
    #pragma unroll 1
    for (int it = 0; it < 5; ++it) {
        const int t0 = 2 * it;
        AFREAD(buf0);                          // tile t0 frags (issue early)
        L1SIG(C0, C1, C2, C3, buf1);           // tile t0+1 (fills latency)
        LOADK(t0 + 2, A0, A1, A2, A3);
        L2L3(t0);
        AFREAD(buf1);                          // tile t0+1 frags
        L1SIG(A0, A1, A2, A3, buf0);           // tile t0+2
        LOADK(t0 + 3, C0, C1, C2, C3);
        L2L3(t0 + 1);
    }
    // epilogue: tiles 10..12 (buf0 holds tile 10; C holds keys of tile 11)
    AFREAD(buf0);
    L1SIG(C0, C1, C2, C3, buf1);               // tile 11
    LOADK(12, A0, A1, A2, A3);
    L2L3(10);
    AFREAD(buf1);
    L1SIG(A0, A1, A2, A3, buf0);               // tile 12
    L2L3(11);
    AFREAD(buf0);
    L2L3(12);
#undef LOADK
#undef L1SIG
#undef AFREAD
#undef L2L3

    // ---------------- wave-local softmax over myred[0..255] ----------------
    float v0 = myred[l], v1 = myred[64 + l], v2 = myred[128 + l], v3 = myred[192 + l];
    float m = fmaxf(fmaxf(v0, v1), fmaxf(v2, v3));
    #pragma unroll
    for (int off = 32; off; off >>= 1) m = fmaxf(m, __shfl_xor(m, off));
    float e0 = __expf(v0 - m), e1 = __expf(v1 - m);
    float e2 = __expf(v2 - m), e3 = __expf(v3 - m);
    float s = (e0 + e1) + (e2 + e3);
    #pragma unroll
    for (int off = 32; off; off >>= 1) s += __shfl_xor(s, off);
    const float is_ = frcp(s);
    myred[l] = e0 * is_; myred[64 + l] = e1 * is_;
    myred[128 + l] = e2 * is_; myred[192 + l] = e3 * is_;

    // ---------------- output: out[b][l] = sum_t attn[t]*keys[b][t][l] ------
    float a0 = 0.f, a1 = 0.f, a2 = 0.f, a3 = 0.f;
    #pragma unroll 2
    for (int t = 0; t < 200; t += 4) {
        a0 = fmaf(myred[t],     kb[(t)     * 64 + l], a0);
        a1 = fmaf(myred[t + 1], kb[(t + 1) * 64 + l], a1);
        a2 = fmaf(myred[t + 2], kb[(t + 2) * 64 + l], a2);
        a3 = fmaf(myred[t + 3], kb[(t + 3) * 64 + l], a3);
    }
    out[b * 64 + l] = (a0 + a1) + (a2 + a3);
}

extern "C" void kernel_launch(void* const* d_in, const int* in_sizes, int n_in,
                              void* d_out, int out_size, void* d_ws, size_t ws_size,
                              hipStream_t stream) {
    const float* q    = (const float*)d_in[0];
    const float* keys = (const float*)d_in[1];
    const int*   kl   = (const int*)d_in[2];
    const float* W1   = (const float*)d_in[3];
    const float* b1   = (const float*)d_in[4];
    const float* W2   = (const float*)d_in[5];
    const float* b2   = (const float*)d_in[6];
    const float* W3   = (const float*)d_in[7];
    const float* b3   = (const float*)d_in[8];

    unsigned short* w1f = (unsigned short*)d_ws;            // 10240 bf16
    unsigned short* w2f = w1f + 10240;                      //  4608 bf16
    float* wqf   = (float*)((char*)d_ws + 32768);           //  5120 f32
    float* hinit = wqf + 5120;                              // 327680 f32

    fold_weights<<<(19968 + 255) / 256, 256, 0, stream>>>(W1, W2, w1f, w2f, wqf);
    hinit_kernel<<<(B_ * 80 + 255) / 256, 256, 0, stream>>>(q, wqf, b1, hinit);
    din_attn<<<B_ / 4, NT, 0, stream>>>(q, keys, kl, hinit, w1f, w2f, b2, W3, b3,
                                        (float*)d_out);
}

// Round 11
// 84.775 us; speedup vs baseline: 1.7983x; 1.0333x over previous
//
#include <hip/hip_runtime.h>
#include <math.h>

constexpr int B_ = 4096, T_ = 200, D_ = 64, NT = 256;
constexpr float NEG_INF_F = -4294967295.0f;  // float32(-2^32+1)

typedef __attribute__((ext_vector_type(8))) __bf16 bf16x8;
typedef __attribute__((ext_vector_type(4))) float f32x4;

__device__ __host__ inline unsigned short f2b_rne(float x) {
    unsigned u = __builtin_bit_cast(unsigned, x);
    u += 0x7FFF + ((u >> 16) & 1);
    return (unsigned short)(u >> 16);
}

__device__ inline unsigned short b16bits(float x) {
    return __builtin_bit_cast(unsigned short, (__bf16)x);
}

__device__ inline float frcp(float x) { return __builtin_amdgcn_rcpf(x); }

__device__ inline bf16x8 pack8(float4 lo, float4 hi) {
    bf16x8 r;
    r[0] = (__bf16)lo.x; r[1] = (__bf16)lo.y; r[2] = (__bf16)lo.z; r[3] = (__bf16)lo.w;
    r[4] = (__bf16)hi.x; r[5] = (__bf16)hi.y; r[6] = (__bf16)hi.z; r[7] = (__bf16)hi.w;
    return r;
}

// ---------------------------------------------------------------------------
// Fold weights into MFMA-fragment order (bf16). Same layouts as round 3.
// ---------------------------------------------------------------------------
__global__ void fold_weights(const float* __restrict__ W1,
                             const float* __restrict__ W2,
                             unsigned short* __restrict__ w1f,
                             unsigned short* __restrict__ w2f,
                             float* __restrict__ wqf) {
    int i = blockIdx.x * blockDim.x + threadIdx.x;
    if (i < 10240) {
        int j = i & 7, lane = (i >> 3) & 63, nt = (i >> 9) % 5, s = i / 2560;
        int k = s * 32 + (lane >> 4) * 8 + j;
        int n = nt * 16 + (lane & 15);
        float v = (k < 64) ? W1[(64 + k) * 80 + n] - W1[(128 + k) * 80 + n]
                           : W1[(192 + (k - 64)) * 80 + n];
        w1f[i] = f2b_rne(v);
    } else if (i < 14848) {
        int i2 = i - 10240;
        int j = i2 & 7, lane = (i2 >> 3) & 63, nt = (i2 >> 9) % 3, s = i2 / 1536;
        int k = s * 32 + (lane >> 4) * 8 + j;
        int n = nt * 16 + (lane & 15);
        float v = (k < 80 && n < 40) ? W2[k * 40 + n] : 0.f;
        w2f[i2] = f2b_rne(v);
    } else if (i < 19968) {
        int i3 = i - 14848;
        int n = i3 % 80, d = i3 / 80;
        wqf[i3] = W1[d * 80 + n] + W1[(128 + d) * 80 + n];
    }
}

__global__ __launch_bounds__(256)
void hinit_kernel(const float* __restrict__ q, const float* __restrict__ wqf,
                  const float* __restrict__ b1, float* __restrict__ hinit) {
    int i = blockIdx.x * blockDim.x + threadIdx.x;
    if (i >= B_ * 80) return;
    int b = i / 80, n = i - b * 80;
    const float* qr = q + b * 64;
    float acc = b1[n];
    #pragma unroll 8
    for (int d = 0; d < 64; ++d) acc = fmaf(qr[d], wqf[d * 80 + n], acc);
    hinit[i] = acc;
}

// ---------------------------------------------------------------------------
// Main kernel (round-10 structure + output-pass MLP fix): one wave = one
// batch row, barrier-free, W_eff in registers, rcp sigmoid, 2-tile pipeline.
// NEW: output pass uses lane-owns-d-quad float4 loads (50 dwordx4 instead of
// 200 dword -> 4x memory-level parallelism on the serial tail).
// ---------------------------------------------------------------------------
__global__ __launch_bounds__(NT, 2)
void din_attn(const float* __restrict__ q, const float* __restrict__ keys,
              const int* __restrict__ klen, const float* __restrict__ hinit_g,
              const unsigned short* __restrict__ w1f,
              const unsigned short* __restrict__ w2f,
              const float* __restrict__ b2, const float* __restrict__ W3,
              const float* __restrict__ b3, float* __restrict__ out) {
    const int tid = threadIdx.x;
    const int l = tid & 63, wid = tid >> 6, g4 = l >> 4, ln = l & 15;
    const int b = blockIdx.x * 4 + wid;

    alignas(16) __shared__ unsigned short h1c[4][2][16 * 104]; // 26.6 KB dbuf
    __shared__ float red[4][256];                              // 4 KB

    float* myred = red[wid];
    unsigned short* buf0 = h1c[wid][0];
    unsigned short* buf1 = h1c[wid][1];
    if (l >= 8) myred[192 + l] = -INFINITY;   // pad rows 200..255 (own-wave)
    #pragma unroll
    for (int r = 0; r < 4; ++r) {             // zero pad cols 80..95 once
        buf0[(g4 * 4 + r) * 104 + 80 + ln] = 0;
        buf1[(g4 * 4 + r) * 104 + 80 + ln] = 0;
    }

    const int len = klen[b];
    const float b3v = b3[0];

    float hv[5], b2v[3], w3v[3];
    const float* hb = hinit_g + b * 80;
    #pragma unroll
    for (int nt = 0; nt < 5; ++nt) hv[nt] = hb[nt * 16 + ln];
    #pragma unroll
    for (int nt = 0; nt < 3; ++nt) {
        int idx = nt * 16 + ln;
        b2v[nt] = (idx < 40) ? b2[idx] : 0.f;
        w3v[nt] = (idx < 40) ? W3[idx] : 0.f;
    }

    const float* qb = q + b * 64;
    float4 q0  = *(const float4*)(qb + g4 * 8);
    float4 q0b = *(const float4*)(qb + g4 * 8 + 4);
    float4 q1  = *(const float4*)(qb + 32 + g4 * 8);
    float4 q1b = *(const float4*)(qb + 32 + g4 * 8 + 4);

    // ---- build W_eff = Wk + q (.) Wqk as 10 register B-frags (once/row) ----
    bf16x8 wf_[2][5];
    #pragma unroll
    for (int s = 0; s < 2; ++s) {
        float qa0 = (s == 0) ? q0.x  : q1.x,  qa1 = (s == 0) ? q0.y  : q1.y;
        float qa2 = (s == 0) ? q0.z  : q1.z,  qa3 = (s == 0) ? q0.w  : q1.w;
        float qb0 = (s == 0) ? q0b.x : q1b.x, qb1 = (s == 0) ? q0b.y : q1b.y;
        float qb2 = (s == 0) ? q0b.z : q1b.z, qb3 = (s == 0) ? q0b.w : q1b.w;
        #pragma unroll
        for (int nt = 0; nt < 5; ++nt) {
            bf16x8 wk = *(const bf16x8*)&w1f[((s * 5 + nt) * 64 + l) * 8];
            bf16x8 wq = *(const bf16x8*)&w1f[(((s + 2) * 5 + nt) * 64 + l) * 8];
            bf16x8 r;
            r[0] = (__bf16)fmaf(qa0, (float)wq[0], (float)wk[0]);
            r[1] = (__bf16)fmaf(qa1, (float)wq[1], (float)wk[1]);
            r[2] = (__bf16)fmaf(qa2, (float)wq[2], (float)wk[2]);
            r[3] = (__bf16)fmaf(qa3, (float)wq[3], (float)wk[3]);
            r[4] = (__bf16)fmaf(qb0, (float)wq[4], (float)wk[4]);
            r[5] = (__bf16)fmaf(qb1, (float)wq[5], (float)wk[5]);
            r[6] = (__bf16)fmaf(qb2, (float)wq[6], (float)wk[6]);
            r[7] = (__bf16)fmaf(qb3, (float)wq[7], (float)wk[7]);
            wf_[s][nt] = r;
        }
    }

    const float* kb = keys + (size_t)b * 200 * 64;

#define LOADK(tile_, B0_, B1_, B2_, B3_) do {                              \
        int t_ = (tile_) * 16 + ln;                                        \
        int tc_ = t_ < 200 ? t_ : 199;                                     \
        const float* row_ = kb + tc_ * 64;                                 \
        B0_ = *(const float4*)(row_ + g4 * 8);                             \
        B1_ = *(const float4*)(row_ + g4 * 8 + 4);                         \
        B2_ = *(const float4*)(row_ + 32 + g4 * 8);                        \
        B3_ = *(const float4*)(row_ + 32 + g4 * 8 + 4);                    \
    } while (0)

#define L1SIG(K0_, K1_, K2_, K3_, DST_) do {                               \
        f32x4 acc[5];                                                      \
        _Pragma("unroll")                                                  \
        for (int nt = 0; nt < 5; ++nt)                                     \
            acc[nt] = (f32x4){hv[nt], hv[nt], hv[nt], hv[nt]};             \
        bf16x8 av0 = pack8(K0_, K1_);                                      \
        bf16x8 av1 = pack8(K2_, K3_);                                      \
        _Pragma("unroll")                                                  \
        for (int nt = 0; nt < 5; ++nt) {                                   \
            acc[nt] = __builtin_amdgcn_mfma_f32_16x16x32_bf16(             \
                av0, wf_[0][nt], acc[nt], 0, 0, 0);                        \
            acc[nt] = __builtin_amdgcn_mfma_f32_16x16x32_bf16(             \
                av1, wf_[1][nt], acc[nt], 0, 0, 0);                        \
        }                                                                  \
        _Pragma("unroll")                                                  \
        for (int nt = 0; nt < 5; ++nt)                                     \
            _Pragma("unroll")                                              \
            for (int r = 0; r < 4; ++r) {                                  \
                float sg = frcp(1.f + __expf(-acc[nt][r]));                \
                (DST_)[(g4 * 4 + r) * 104 + nt * 16 + ln] = b16bits(sg);   \
            }                                                              \
    } while (0)

#define AFREAD(SRC_) do {                                                  \
        af0 = *(const bf16x8*)((SRC_) + ln * 104 + g4 * 8);                \
        af1 = *(const bf16x8*)((SRC_) + ln * 104 + 32 + g4 * 8);           \
        af2 = *(const bf16x8*)((SRC_) + ln * 104 + 64 + g4 * 8);           \
    } while (0)

#define L2L3(tile_) do {                                                   \
        f32x4 acc2[3];                                                     \
        _Pragma("unroll")                                                  \
        for (int nt = 0; nt < 3; ++nt)                                     \
            acc2[nt] = (f32x4){b2v[nt], b2v[nt], b2v[nt], b2v[nt]};        \
        _Pragma("unroll")                                                  \
        for (int nt = 0; nt < 3; ++nt) {                                   \
            bf16x8 w0_ = *(const bf16x8*)(w2f + ((0 * 3 + nt) * 64 + l) * 8); \
            bf16x8 w1_ = *(const bf16x8*)(w2f + ((1 * 3 + nt) * 64 + l) * 8); \
            bf16x8 w2_ = *(const bf16x8*)(w2f + ((2 * 3 + nt) * 64 + l) * 8); \
            acc2[nt] = __builtin_amdgcn_mfma_f32_16x16x32_bf16(af0, w0_, acc2[nt], 0, 0, 0); \
            acc2[nt] = __builtin_amdgcn_mfma_f32_16x16x32_bf16(af1, w1_, acc2[nt], 0, 0, 0); \
            acc2[nt] = __builtin_amdgcn_mfma_f32_16x16x32_bf16(af2, w2_, acc2[nt], 0, 0, 0); \
        }                                                                  \
        _Pragma("unroll")                                                  \
        for (int r = 0; r < 4; ++r) {                                      \
            float p = w3v[0] * frcp(1.f + __expf(-acc2[0][r]))             \
                    + w3v[1] * frcp(1.f + __expf(-acc2[1][r]))             \
                    + w3v[2] * frcp(1.f + __expf(-acc2[2][r]));            \
            p += __shfl_xor(p, 1); p += __shfl_xor(p, 2);                  \
            p += __shfl_xor(p, 4); p += __shfl_xor(p, 8);                  \
            if (ln == 0) {                                                 \
                int trow = (tile_) * 16 + g4 * 4 + r;                      \
                if (trow < 200)                                            \
                    myred[trow] = (trow < len) ? (p + b3v) * 0.125f        \
                                               : NEG_INF_F * 0.125f;       \
            }                                                              \
        }                                                                  \
    } while (0)

    // ---- 2-tile pipeline: L1(i+1) overlaps the LDS round-trip of L2(i) ----
    float4 A0, A1, A2, A3, C0, C1, C2, C3;
    bf16x8 af0, af1, af2;
    LOADK(0, A0, A1, A2, A3);
    L1SIG(A0, A1, A2, A3, buf0);
    LOADK(1, C0, C1, C2, C3);
    #pragma unroll 1
    for (int it = 0; it < 5; ++it) {
        const int t0 = 2 * it;
        AFREAD(buf0);                          // tile t0 frags (issue early)
        L1SIG(C0, C1, C2, C3, buf1);           // tile t0+1 (fills latency)
        LOADK(t0 + 2, A0, A1, A2, A3);
        L2L3(t0);
        AFREAD(buf1);                          // tile t0+1 frags
        L1SIG(A0, A1, A2, A3, buf0);           // tile t0+2
        LOADK(t0 + 3, C0, C1, C2, C3);
        L2L3(t0 + 1);
    }
    // epilogue: tiles 10..12 (buf0 holds tile 10; C holds keys of tile 11)
    AFREAD(buf0);
    L1SIG(C0, C1, C2, C3, buf1);               // tile 11
    LOADK(12, A0, A1, A2, A3);
    L2L3(10);
    AFREAD(buf1);
    L1SIG(A0, A1, A2, A3, buf0);               // tile 12
    L2L3(11);
    AFREAD(buf0);
    L2L3(12);
#undef LOADK
#undef L1SIG
#undef AFREAD
#undef L2L3

    // ---------------- wave-local softmax over myred[0..255] ----------------
    float v0 = myred[l], v1 = myred[64 + l], v2 = myred[128 + l], v3 = myred[192 + l];
    float m = fmaxf(fmaxf(v0, v1), fmaxf(v2, v3));
    #pragma unroll
    for (int off = 32; off; off >>= 1) m = fmaxf(m, __shfl_xor(m, off));
    float e0 = __expf(v0 - m), e1 = __expf(v1 - m);
    float e2 = __expf(v2 - m), e3 = __expf(v3 - m);
    float s = (e0 + e1) + (e2 + e3);
    #pragma unroll
    for (int off = 32; off; off >>= 1) s += __shfl_xor(s, off);
    const float is_ = frcp(s);
    myred[l] = e0 * is_; myred[64 + l] = e1 * is_;
    myred[128 + l] = e2 * is_; myred[192 + l] = e3 * is_;

    // -------- output: lane owns d-quad [4*ln..4*ln+3], t = g4 (mod 4) ------
    // 50 dwordx4 loads (vs 200 dword): 4x bytes per outstanding load slot.
    {
        float4 oq = {0.f, 0.f, 0.f, 0.f};
        #pragma unroll 5
        for (int t = g4; t < 200; t += 4) {
            float w = myred[t];                      // 4 banks, broadcast x16
            float4 kv = *(const float4*)(kb + t * 64 + 4 * ln);
            oq.x = fmaf(w, kv.x, oq.x); oq.y = fmaf(w, kv.y, oq.y);
            oq.z = fmaf(w, kv.z, oq.z); oq.w = fmaf(w, kv.w, oq.w);
        }
        // reduce the 4 g4-group partials for each d-quad
        oq.x += __shfl_xor(oq.x, 16); oq.x += __shfl_xor(oq.x, 32);
        oq.y += __shfl_xor(oq.y, 16); oq.y += __shfl_xor(oq.y, 32);
        oq.z += __shfl_xor(oq.z, 16); oq.z += __shfl_xor(oq.z, 32);
        oq.w += __shfl_xor(oq.w, 16); oq.w += __shfl_xor(oq.w, 32);
        if (g4 == 0)
            *(float4*)(out + b * 64 + 4 * ln) = oq;  // coalesced 256B store
    }
}

extern "C" void kernel_launch(void* const* d_in, const int* in_sizes, int n_in,
                              void* d_out, int out_size, void* d_ws, size_t ws_size,
                              hipStream_t stream) {
    const float* q    = (const float*)d_in[0];
    const float* keys = (const float*)d_in[1];
    const int*   kl   = (const int*)d_in[2];
    const float* W1   = (const float*)d_in[3];
    const float* b1   = (const float*)d_in[4];
    const float* W2   = (const float*)d_in[5];
    const float* b2   = (const float*)d_in[6];
    const float* W3   = (const float*)d_in[7];
    const float* b3   = (const float*)d_in[8];

    unsigned short* w1f = (unsigned short*)d_ws;            // 10240 bf16
    unsigned short* w2f = w1f + 10240;                      //  4608 bf16
    float* wqf   = (float*)((char*)d_ws + 32768);           //  5120 f32
    float* hinit = wqf + 5120;                              // 327680 f32

    fold_weights<<<(19968 + 255) / 256, 256, 0, stream>>>(W1, W2, w1f, w2f, wqf);
    hinit_kernel<<<(B_ * 80 + 255) / 256, 256, 0, stream>>>(q, wqf, b1, hinit);
    din_attn<<<B_ / 4, NT, 0, stream>>>(q, keys, kl, hinit, w1f, w2f, b2, W3, b3,
                                        (float*)d_out);
}

// Round 12
// 77.757 us; speedup vs baseline: 1.9606x; 1.0903x over previous
//
#include <hip/hip_runtime.h>
#include <math.h>

constexpr int B_ = 4096, T_ = 200, D_ = 64, NT = 256;
constexpr float NEG_INF_F = -4294967295.0f;  // float32(-2^32+1)
constexpr float LOG2E = 1.4426950408889634f;

typedef __attribute__((ext_vector_type(8))) __bf16 bf16x8;
typedef __attribute__((ext_vector_type(4))) float f32x4;

__device__ __host__ inline unsigned short f2b_rne(float x) {
    unsigned u = __builtin_bit_cast(unsigned, x);
    u += 0x7FFF + ((u >> 16) & 1);
    return (unsigned short)(u >> 16);
}

__device__ inline unsigned short b16bits(float x) {
    return __builtin_bit_cast(unsigned short, (__bf16)x);
}

__device__ inline float frcp(float x) { return __builtin_amdgcn_rcpf(x); }

__device__ inline float fexp2(float x) {
#if __has_builtin(__builtin_amdgcn_exp2f)
    return __builtin_amdgcn_exp2f(x);
#else
    return exp2f(x);
#endif
}

__device__ inline bf16x8 pack8(float4 lo, float4 hi) {
    bf16x8 r;
    r[0] = (__bf16)lo.x; r[1] = (__bf16)lo.y; r[2] = (__bf16)lo.z; r[3] = (__bf16)lo.w;
    r[4] = (__bf16)hi.x; r[5] = (__bf16)hi.y; r[6] = (__bf16)hi.z; r[7] = (__bf16)hi.w;
    return r;
}

// ---------------------------------------------------------------------------
// Fold weights into MFMA-fragment order (bf16), PRE-SCALED by log2(e) so the
// kernel's sigmoids use raw v_exp (2^x) with no per-element multiply.
// w1f  [s=0..3][nt=0..4][lane][j]: s<2 Wk = W1[64+k][n]-W1[128+k][n]; s>=2 Wqk.
// w2f  [s=0..2][nt=0..2][lane][j]: W2 padded [96][48].
// wqff [s=0..1][nt=0..4][lane][j]: Wq_sum = W1[d][n]+W1[128+d][n] (hinit B-frags).
// ---------------------------------------------------------------------------
__global__ void fold_weights(const float* __restrict__ W1,
                             const float* __restrict__ W2,
                             unsigned short* __restrict__ w1f,
                             unsigned short* __restrict__ w2f,
                             unsigned short* __restrict__ wqff) {
    int i = blockIdx.x * blockDim.x + threadIdx.x;
    if (i < 10240) {
        int j = i & 7, lane = (i >> 3) & 63, nt = (i >> 9) % 5, s = i / 2560;
        int k = s * 32 + (lane >> 4) * 8 + j;
        int n = nt * 16 + (lane & 15);
        float v = (k < 64) ? W1[(64 + k) * 80 + n] - W1[(128 + k) * 80 + n]
                           : W1[(192 + (k - 64)) * 80 + n];
        w1f[i] = f2b_rne(v * LOG2E);
    } else if (i < 14848) {
        int i2 = i - 10240;
        int j = i2 & 7, lane = (i2 >> 3) & 63, nt = (i2 >> 9) % 3, s = i2 / 1536;
        int k = s * 32 + (lane >> 4) * 8 + j;
        int n = nt * 16 + (lane & 15);
        float v = (k < 80 && n < 40) ? W2[k * 40 + n] * LOG2E : 0.f;
        w2f[i2] = f2b_rne(v);
    } else if (i < 19968) {
        int i3 = i - 14848;
        int j = i3 & 7, lane = (i3 >> 3) & 63, nt = (i3 >> 9) % 5, s = i3 / 2560;
        int d = s * 32 + (lane >> 4) * 8 + j;
        int n = nt * 16 + (lane & 15);
        wqff[i3] = f2b_rne((W1[d * 80 + n] + W1[(128 + d) * 80 + n]) * LOG2E);
    }
}

// ---------------------------------------------------------------------------
// Main kernel: one wave = one batch row, barrier-free. W_eff in registers,
// 2-tile pipeline, exp2-sigmoid (weights pre-scaled by log2e), hinit computed
// IN-KERNEL via 10 one-time MFMAs (hinit_kernel deleted), cursor-based keys
// addressing (constant 4KB/tile increment; only peeled tile 12 clamps).
// ---------------------------------------------------------------------------
__global__ __launch_bounds__(NT, 2)
void din_attn(const float* __restrict__ q, const float* __restrict__ keys,
              const int* __restrict__ klen,
              const unsigned short* __restrict__ w1f,
              const unsigned short* __restrict__ w2f,
              const unsigned short* __restrict__ wqff,
              const float* __restrict__ b1, const float* __restrict__ b2,
              const float* __restrict__ W3, const float* __restrict__ b3,
              float* __restrict__ out) {
    const int tid = threadIdx.x;
    const int l = tid & 63, wid = tid >> 6, g4 = l >> 4, ln = l & 15;
    const int b = blockIdx.x * 4 + wid;

    alignas(16) __shared__ unsigned short h1c[4][2][16 * 104]; // 26.6 KB dbuf
    __shared__ float red[4][256];                              // 4 KB

    float* myred = red[wid];
    unsigned short* buf0 = h1c[wid][0];
    unsigned short* buf1 = h1c[wid][1];
    if (l >= 8) myred[192 + l] = -INFINITY;   // pad rows 200..255 (own-wave)
    #pragma unroll
    for (int r = 0; r < 4; ++r) {             // zero pad cols 80..95 once
        buf0[(g4 * 4 + r) * 104 + 80 + ln] = 0;
        buf1[(g4 * 4 + r) * 104 + 80 + ln] = 0;
    }

    const int len = klen[b];
    const float b3v = b3[0];

    float b2v[3], w3v[3];
    #pragma unroll
    for (int nt = 0; nt < 3; ++nt) {
        int idx = nt * 16 + ln;
        b2v[nt] = (idx < 40) ? b2[idx] * LOG2E : 0.f;
        w3v[nt] = (idx < 40) ? W3[idx] : 0.f;
    }

    const float* qb = q + b * 64;
    float4 q0  = *(const float4*)(qb + g4 * 8);
    float4 q0b = *(const float4*)(qb + g4 * 8 + 4);
    float4 q1  = *(const float4*)(qb + 32 + g4 * 8);
    float4 q1b = *(const float4*)(qb + 32 + g4 * 8 + 4);
    bf16x8 qf0 = pack8(q0, q0b);
    bf16x8 qf1 = pack8(q1, q1b);

    // ---- hinit via 10 MFMA: all A rows = q  =>  every acc row = hinit ----
    float hv[5];
    {
        f32x4 hacc[5];
        #pragma unroll
        for (int nt = 0; nt < 5; ++nt) {
            float bv = b1[nt * 16 + ln] * LOG2E;
            hacc[nt] = (f32x4){bv, bv, bv, bv};
        }
        #pragma unroll
        for (int nt = 0; nt < 5; ++nt) {
            bf16x8 f0 = *(const bf16x8*)&wqff[((0 * 5 + nt) * 64 + l) * 8];
            bf16x8 f1 = *(const bf16x8*)&wqff[((1 * 5 + nt) * 64 + l) * 8];
            hacc[nt] = __builtin_amdgcn_mfma_f32_16x16x32_bf16(qf0, f0, hacc[nt], 0, 0, 0);
            hacc[nt] = __builtin_amdgcn_mfma_f32_16x16x32_bf16(qf1, f1, hacc[nt], 0, 0, 0);
        }
        #pragma unroll
        for (int nt = 0; nt < 5; ++nt) hv[nt] = hacc[nt][0];
    }

    // ---- build W_eff = Wk + q (.) Wqk as 10 register B-frags (once/row) ----
    bf16x8 wf_[2][5];
    #pragma unroll
    for (int s = 0; s < 2; ++s) {
        float qa0 = (s == 0) ? q0.x  : q1.x,  qa1 = (s == 0) ? q0.y  : q1.y;
        float qa2 = (s == 0) ? q0.z  : q1.z,  qa3 = (s == 0) ? q0.w  : q1.w;
        float qb0 = (s == 0) ? q0b.x : q1b.x, qb1 = (s == 0) ? q0b.y : q1b.y;
        float qb2 = (s == 0) ? q0b.z : q1b.z, qb3 = (s == 0) ? q0b.w : q1b.w;
        #pragma unroll
        for (int nt = 0; nt < 5; ++nt) {
            bf16x8 wk = *(const bf16x8*)&w1f[((s * 5 + nt) * 64 + l) * 8];
            bf16x8 wq = *(const bf16x8*)&w1f[(((s + 2) * 5 + nt) * 64 + l) * 8];
            bf16x8 r;
            r[0] = (__bf16)fmaf(qa0, (float)wq[0], (float)wk[0]);
            r[1] = (__bf16)fmaf(qa1, (float)wq[1], (float)wk[1]);
            r[2] = (__bf16)fmaf(qa2, (float)wq[2], (float)wk[2]);
            r[3] = (__bf16)fmaf(qa3, (float)wq[3], (float)wk[3]);
            r[4] = (__bf16)fmaf(qb0, (float)wq[4], (float)wk[4]);
            r[5] = (__bf16)fmaf(qb1, (float)wq[5], (float)wk[5]);
            r[6] = (__bf16)fmaf(qb2, (float)wq[6], (float)wk[6]);
            r[7] = (__bf16)fmaf(qb3, (float)wq[7], (float)wk[7]);
            wf_[s][nt] = r;
        }
    }

    const float* kb = keys + (size_t)b * 200 * 64;
    const float* cur = kb + ln * 64 + g4 * 8;   // advances 1024 floats/tile

#define LOADK_CUR(B0_, B1_, B2_, B3_) do {                                 \
        B0_ = *(const float4*)(cur);                                       \
        B1_ = *(const float4*)(cur + 4);                                   \
        B2_ = *(const float4*)(cur + 32);                                  \
        B3_ = *(const float4*)(cur + 36);                                  \
        cur += 1024;                                                       \
    } while (0)

#define L1SIG(K0_, K1_, K2_, K3_, DST_) do {                               \
        f32x4 acc[5];                                                      \
        _Pragma("unroll")                                                  \
        for (int nt = 0; nt < 5; ++nt)                                     \
            acc[nt] = (f32x4){hv[nt], hv[nt], hv[nt], hv[nt]};             \
        bf16x8 av0 = pack8(K0_, K1_);                                      \
        bf16x8 av1 = pack8(K2_, K3_);                                      \
        _Pragma("unroll")                                                  \
        for (int nt = 0; nt < 5; ++nt) {                                   \
            acc[nt] = __builtin_amdgcn_mfma_f32_16x16x32_bf16(             \
                av0, wf_[0][nt], acc[nt], 0, 0, 0);                        \
            acc[nt] = __builtin_amdgcn_mfma_f32_16x16x32_bf16(             \
                av1, wf_[1][nt], acc[nt], 0, 0, 0);                        \
        }                                                                  \
        _Pragma("unroll")                                                  \
        for (int nt = 0; nt < 5; ++nt)                                     \
            _Pragma("unroll")                                              \
            for (int r = 0; r < 4; ++r) {                                  \
                float sg = frcp(1.f + fexp2(-acc[nt][r]));                 \
                (DST_)[(g4 * 4 + r) * 104 + nt * 16 + ln] = b16bits(sg);   \
            }                                                              \
    } while (0)

#define AFREAD(SRC_) do {                                                  \
        af0 = *(const bf16x8*)((SRC_) + ln * 104 + g4 * 8);                \
        af1 = *(const bf16x8*)((SRC_) + ln * 104 + 32 + g4 * 8);           \
        af2 = *(const bf16x8*)((SRC_) + ln * 104 + 64 + g4 * 8);           \
    } while (0)

#define L2L3(tile_) do {                                                   \
        f32x4 acc2[3];                                                     \
        _Pragma("unroll")                                                  \
        for (int nt = 0; nt < 3; ++nt)                                     \
            acc2[nt] = (f32x4){b2v[nt], b2v[nt], b2v[nt], b2v[nt]};        \
        _Pragma("unroll")                                                  \
        for (int nt = 0; nt < 3; ++nt) {                                   \
            bf16x8 w0_ = *(const bf16x8*)(w2f + ((0 * 3 + nt) * 64 + l) * 8); \
            bf16x8 w1_ = *(const bf16x8*)(w2f + ((1 * 3 + nt) * 64 + l) * 8); \
            bf16x8 w2_ = *(const bf16x8*)(w2f + ((2 * 3 + nt) * 64 + l) * 8); \
            acc2[nt] = __builtin_amdgcn_mfma_f32_16x16x32_bf16(af0, w0_, acc2[nt], 0, 0, 0); \
            acc2[nt] = __builtin_amdgcn_mfma_f32_16x16x32_bf16(af1, w1_, acc2[nt], 0, 0, 0); \
            acc2[nt] = __builtin_amdgcn_mfma_f32_16x16x32_bf16(af2, w2_, acc2[nt], 0, 0, 0); \
        }                                                                  \
        _Pragma("unroll")                                                  \
        for (int r = 0; r < 4; ++r) {                                      \
            float p = w3v[0] * frcp(1.f + fexp2(-acc2[0][r]))              \
                    + w3v[1] * frcp(1.f + fexp2(-acc2[1][r]))              \
                    + w3v[2] * frcp(1.f + fexp2(-acc2[2][r]));             \
            p += __shfl_xor(p, 1); p += __shfl_xor(p, 2);                  \
            p += __shfl_xor(p, 4); p += __shfl_xor(p, 8);                  \
            if (ln == 0) {                                                 \
                int trow = (tile_) * 16 + g4 * 4 + r;                      \
                if (trow < 200)                                            \
                    myred[trow] = (trow < len)                             \
                        ? (p + b3v) * (0.125f * LOG2E)                     \
                        : NEG_INF_F * (0.125f * LOG2E);                    \
            }                                                              \
        }                                                                  \
    } while (0)

    // ---- 2-tile pipeline: L1(i+1) overlaps the LDS round-trip of L2(i) ----
    float4 A0, A1, A2, A3, C0, C1, C2, C3;
    bf16x8 af0, af1, af2;
    LOADK_CUR(A0, A1, A2, A3);                 // tile 0
    L1SIG(A0, A1, A2, A3, buf0);
    LOADK_CUR(C0, C1, C2, C3);                 // tile 1
    #pragma unroll 1
    for (int it = 0; it < 5; ++it) {
        const int t0 = 2 * it;
        AFREAD(buf0);                          // tile t0 frags (issue early)
        L1SIG(C0, C1, C2, C3, buf1);           // tile t0+1 (fills latency)
        LOADK_CUR(A0, A1, A2, A3);             // tile t0+2
        L2L3(t0);
        AFREAD(buf1);                          // tile t0+1 frags
        L1SIG(A0, A1, A2, A3, buf0);           // tile t0+2
        LOADK_CUR(C0, C1, C2, C3);             // tile t0+3
        L2L3(t0 + 1);
    }
    // epilogue: tiles 10..12 (buf0 = tile 10; C = keys of tile 11)
    AFREAD(buf0);
    L1SIG(C0, C1, C2, C3, buf1);               // tile 11
    {   // peeled tile-12 load (clamped rows 200..207 -> 199)
        int tc = 192 + ln; if (tc > 199) tc = 199;
        const float* r12 = kb + tc * 64 + g4 * 8;
        A0 = *(const float4*)(r12);
        A1 = *(const float4*)(r12 + 4);
        A2 = *(const float4*)(r12 + 32);
        A3 = *(const float4*)(r12 + 36);
    }
    L2L3(10);
    AFREAD(buf1);
    L1SIG(A0, A1, A2, A3, buf0);               // tile 12
    L2L3(11);
    AFREAD(buf0);
    L2L3(12);
#undef LOADK_CUR
#undef L1SIG
#undef AFREAD
#undef L2L3

    // ------------- wave-local softmax over myred[0..255] (exp2) -----------
    float v0 = myred[l], v1 = myred[64 + l], v2 = myred[128 + l], v3 = myred[192 + l];
    float m = fmaxf(fmaxf(v0, v1), fmaxf(v2, v3));
    #pragma unroll
    for (int off = 32; off; off >>= 1) m = fmaxf(m, __shfl_xor(m, off));
    float e0 = fexp2(v0 - m), e1 = fexp2(v1 - m);
    float e2 = fexp2(v2 - m), e3 = fexp2(v3 - m);
    float s = (e0 + e1) + (e2 + e3);
    #pragma unroll
    for (int off = 32; off; off >>= 1) s += __shfl_xor(s, off);
    const float is_ = frcp(s);
    myred[l] = e0 * is_; myred[64 + l] = e1 * is_;
    myred[128 + l] = e2 * is_; myred[192 + l] = e3 * is_;

    // -------- output: lane owns d-quad [4*ln..4*ln+3], t = g4 (mod 4) ------
    {
        float4 oq = {0.f, 0.f, 0.f, 0.f};
        #pragma unroll 5
        for (int t = g4; t < 200; t += 4) {
            float w = myred[t];
            float4 kv = *(const float4*)(kb + t * 64 + 4 * ln);
            oq.x = fmaf(w, kv.x, oq.x); oq.y = fmaf(w, kv.y, oq.y);
            oq.z = fmaf(w, kv.z, oq.z); oq.w = fmaf(w, kv.w, oq.w);
        }
        oq.x += __shfl_xor(oq.x, 16); oq.x += __shfl_xor(oq.x, 32);
        oq.y += __shfl_xor(oq.y, 16); oq.y += __shfl_xor(oq.y, 32);
        oq.z += __shfl_xor(oq.z, 16); oq.z += __shfl_xor(oq.z, 32);
        oq.w += __shfl_xor(oq.w, 16); oq.w += __shfl_xor(oq.w, 32);
        if (g4 == 0)
            *(float4*)(out + b * 64 + 4 * ln) = oq;
    }
}

extern "C" void kernel_launch(void* const* d_in, const int* in_sizes, int n_in,
                              void* d_out, int out_size, void* d_ws, size_t ws_size,
                              hipStream_t stream) {
    const float* q    = (const float*)d_in[0];
    const float* keys = (const float*)d_in[1];
    const int*   kl   = (const int*)d_in[2];
    const float* W1   = (const float*)d_in[3];
    const float* b1   = (const float*)d_in[4];
    const float* W2   = (const float*)d_in[5];
    const float* b2   = (const float*)d_in[6];
    const float* W3   = (const float*)d_in[7];
    const float* b3   = (const float*)d_in[8];

    unsigned short* w1f  = (unsigned short*)d_ws;           // 10240 bf16
    unsigned short* w2f  = w1f + 10240;                     //  4608 bf16
    unsigned short* wqff = w2f + 4608;                      //  5120 bf16

    fold_weights<<<(19968 + 255) / 256, 256, 0, stream>>>(W1, W2, w1f, w2f, wqff);
    din_attn<<<B_ / 4, NT, 0, stream>>>(q, keys, kl, w1f, w2f, wqff, b1, b2,
                                        W3, b3, (float*)d_out);
}

// Round 13
// 66.121 us; speedup vs baseline: 2.3057x; 1.1760x over previous
//
#include <hip/hip_runtime.h>
#include <math.h>

constexpr int B_ = 4096, T_ = 200, D_ = 64, NT = 256;
constexpr float NEG_INF_F = -4294967295.0f;  // float32(-2^32+1)
constexpr float LOG2E = 1.4426950408889634f;

typedef __attribute__((ext_vector_type(8))) __bf16 bf16x8;
typedef __attribute__((ext_vector_type(4))) float f32x4;

__device__ __host__ inline unsigned short f2b_rne(float x) {
    unsigned u = __builtin_bit_cast(unsigned, x);
    u += 0x7FFF + ((u >> 16) & 1);
    return (unsigned short)(u >> 16);
}

__device__ inline unsigned short b16bits(float x) {
    return __builtin_bit_cast(unsigned short, (__bf16)x);
}

__device__ inline float frcp(float x) { return __builtin_amdgcn_rcpf(x); }

__device__ inline float fexp2(float x) {
#if __has_builtin(__builtin_amdgcn_exp2f)
    return __builtin_amdgcn_exp2f(x);
#else
    return exp2f(x);
#endif
}

__device__ inline bf16x8 pack8(float4 lo, float4 hi) {
    bf16x8 r;
    r[0] = (__bf16)lo.x; r[1] = (__bf16)lo.y; r[2] = (__bf16)lo.z; r[3] = (__bf16)lo.w;
    r[4] = (__bf16)hi.x; r[5] = (__bf16)hi.y; r[6] = (__bf16)hi.z; r[7] = (__bf16)hi.w;
    return r;
}

// ---------------------------------------------------------------------------
// Fold weights into MFMA-fragment order (bf16), PRE-SCALED by log2(e).
// ---------------------------------------------------------------------------
__global__ void fold_weights(const float* __restrict__ W1,
                             const float* __restrict__ W2,
                             unsigned short* __restrict__ w1f,
                             unsigned short* __restrict__ w2f,
                             unsigned short* __restrict__ wqff) {
    int i = blockIdx.x * blockDim.x + threadIdx.x;
    if (i < 10240) {
        int j = i & 7, lane = (i >> 3) & 63, nt = (i >> 9) % 5, s = i / 2560;
        int k = s * 32 + (lane >> 4) * 8 + j;
        int n = nt * 16 + (lane & 15);
        float v = (k < 64) ? W1[(64 + k) * 80 + n] - W1[(128 + k) * 80 + n]
                           : W1[(192 + (k - 64)) * 80 + n];
        w1f[i] = f2b_rne(v * LOG2E);
    } else if (i < 14848) {
        int i2 = i - 10240;
        int j = i2 & 7, lane = (i2 >> 3) & 63, nt = (i2 >> 9) % 3, s = i2 / 1536;
        int k = s * 32 + (lane >> 4) * 8 + j;
        int n = nt * 16 + (lane & 15);
        float v = (k < 80 && n < 40) ? W2[k * 40 + n] * LOG2E : 0.f;
        w2f[i2] = f2b_rne(v);
    } else if (i < 19968) {
        int i3 = i - 14848;
        int j = i3 & 7, lane = (i3 >> 3) & 63, nt = (i3 >> 9) % 5, s = i3 / 2560;
        int d = s * 32 + (lane >> 4) * 8 + j;
        int n = nt * 16 + (lane & 15);
        wqff[i3] = f2b_rne((W1[d * 80 + n] + W1[(128 + d) * 80 + n]) * LOG2E);
    }
}

// ---------------------------------------------------------------------------
// Main kernel: one wave = one batch row, barrier-free, W_eff in registers,
// 2-tile pipeline, exp2-sigmoid, in-kernel hinit MFMAs.
// NEW: DYNAMIC TILE COUNT ntile = ceil(len/16) — masked tiles produce exactly
// the NEG constant, so skip their MLP entirely (mean len ~100 -> ~47% of tile
// work gone). Output pass also stops at len. len==0 -> ntile=0, all logits =
// NEG (equal) -> uniform softmax over 200 = reference semantics.
// ---------------------------------------------------------------------------
__global__ __launch_bounds__(NT, 2)
void din_attn(const float* __restrict__ q, const float* __restrict__ keys,
              const int* __restrict__ klen,
              const unsigned short* __restrict__ w1f,
              const unsigned short* __restrict__ w2f,
              const unsigned short* __restrict__ wqff,
              const float* __restrict__ b1, const float* __restrict__ b2,
              const float* __restrict__ W3, const float* __restrict__ b3,
              float* __restrict__ out) {
    const int tid = threadIdx.x;
    const int l = tid & 63, wid = tid >> 6, g4 = l >> 4, ln = l & 15;
    const int b = blockIdx.x * 4 + wid;

    alignas(16) __shared__ unsigned short h1c[4][2][16 * 104]; // 26.6 KB dbuf
    __shared__ float red[4][256];                              // 4 KB

    constexpr float NEGS = NEG_INF_F * (0.125f * LOG2E);

    float* myred = red[wid];
    unsigned short* buf0 = h1c[wid][0];
    unsigned short* buf1 = h1c[wid][1];
    // init ALL logits to the masked constant; pads 200..255 to -inf
    myred[l] = NEGS; myred[64 + l] = NEGS; myred[128 + l] = NEGS;
    myred[192 + l] = (l < 8) ? NEGS : -INFINITY;
    #pragma unroll
    for (int r = 0; r < 4; ++r) {             // zero pad cols 80..95 once
        buf0[(g4 * 4 + r) * 104 + 80 + ln] = 0;
        buf1[(g4 * 4 + r) * 104 + 80 + ln] = 0;
    }

    const int len = klen[b];
    const int ntile = (len + 15) >> 4;        // 0..13 active tiles
    const float b3v = b3[0];
    const float* kb = keys + (size_t)b * 200 * 64;

#define LOADK(tile_, B0_, B1_, B2_, B3_) do {                              \
        int t_ = (tile_) * 16 + ln;                                        \
        int tc_ = t_ < 200 ? t_ : 199;                                     \
        const float* row_ = kb + tc_ * 64 + g4 * 8;                        \
        B0_ = *(const float4*)(row_);                                      \
        B1_ = *(const float4*)(row_ + 4);                                  \
        B2_ = *(const float4*)(row_ + 32);                                 \
        B3_ = *(const float4*)(row_ + 36);                                 \
    } while (0)

    if (ntile > 0) {
        float b2v[3], w3v[3];
        #pragma unroll
        for (int nt = 0; nt < 3; ++nt) {
            int idx = nt * 16 + ln;
            b2v[nt] = (idx < 40) ? b2[idx] * LOG2E : 0.f;
            w3v[nt] = (idx < 40) ? W3[idx] : 0.f;
        }

        const float* qb = q + b * 64;
        float4 q0  = *(const float4*)(qb + g4 * 8);
        float4 q0b = *(const float4*)(qb + g4 * 8 + 4);
        float4 q1  = *(const float4*)(qb + 32 + g4 * 8);
        float4 q1b = *(const float4*)(qb + 32 + g4 * 8 + 4);
        bf16x8 qf0 = pack8(q0, q0b);
        bf16x8 qf1 = pack8(q1, q1b);

        // ---- hinit via 10 MFMA: all A rows = q => every acc row = hinit ----
        float hv[5];
        {
            f32x4 hacc[5];
            #pragma unroll
            for (int nt = 0; nt < 5; ++nt) {
                float bv = b1[nt * 16 + ln] * LOG2E;
                hacc[nt] = (f32x4){bv, bv, bv, bv};
            }
            #pragma unroll
            for (int nt = 0; nt < 5; ++nt) {
                bf16x8 f0 = *(const bf16x8*)&wqff[((0 * 5 + nt) * 64 + l) * 8];
                bf16x8 f1 = *(const bf16x8*)&wqff[((1 * 5 + nt) * 64 + l) * 8];
                hacc[nt] = __builtin_amdgcn_mfma_f32_16x16x32_bf16(qf0, f0, hacc[nt], 0, 0, 0);
                hacc[nt] = __builtin_amdgcn_mfma_f32_16x16x32_bf16(qf1, f1, hacc[nt], 0, 0, 0);
            }
            #pragma unroll
            for (int nt = 0; nt < 5; ++nt) hv[nt] = hacc[nt][0];
        }

        // ---- W_eff = Wk + q (.) Wqk as 10 register B-frags (once/row) ----
        bf16x8 wf_[2][5];
        #pragma unroll
        for (int s = 0; s < 2; ++s) {
            float qa0 = (s == 0) ? q0.x  : q1.x,  qa1 = (s == 0) ? q0.y  : q1.y;
            float qa2 = (s == 0) ? q0.z  : q1.z,  qa3 = (s == 0) ? q0.w  : q1.w;
            float qb0 = (s == 0) ? q0b.x : q1b.x, qb1 = (s == 0) ? q0b.y : q1b.y;
            float qb2 = (s == 0) ? q0b.z : q1b.z, qb3 = (s == 0) ? q0b.w : q1b.w;
            #pragma unroll
            for (int nt = 0; nt < 5; ++nt) {
                bf16x8 wk = *(const bf16x8*)&w1f[((s * 5 + nt) * 64 + l) * 8];
                bf16x8 wq = *(const bf16x8*)&w1f[(((s + 2) * 5 + nt) * 64 + l) * 8];
                bf16x8 r;
                r[0] = (__bf16)fmaf(qa0, (float)wq[0], (float)wk[0]);
                r[1] = (__bf16)fmaf(qa1, (float)wq[1], (float)wk[1]);
                r[2] = (__bf16)fmaf(qa2, (float)wq[2], (float)wk[2]);
                r[3] = (__bf16)fmaf(qa3, (float)wq[3], (float)wk[3]);
                r[4] = (__bf16)fmaf(qb0, (float)wq[4], (float)wk[4]);
                r[5] = (__bf16)fmaf(qb1, (float)wq[5], (float)wk[5]);
                r[6] = (__bf16)fmaf(qb2, (float)wq[6], (float)wk[6]);
                r[7] = (__bf16)fmaf(qb3, (float)wq[7], (float)wk[7]);
                wf_[s][nt] = r;
            }
        }

#define L1SIG(K0_, K1_, K2_, K3_, DST_) do {                               \
        f32x4 acc[5];                                                      \
        _Pragma("unroll")                                                  \
        for (int nt = 0; nt < 5; ++nt)                                     \
            acc[nt] = (f32x4){hv[nt], hv[nt], hv[nt], hv[nt]};             \
        bf16x8 av0 = pack8(K0_, K1_);                                      \
        bf16x8 av1 = pack8(K2_, K3_);                                      \
        _Pragma("unroll")                                                  \
        for (int nt = 0; nt < 5; ++nt) {                                   \
            acc[nt] = __builtin_amdgcn_mfma_f32_16x16x32_bf16(             \
                av0, wf_[0][nt], acc[nt], 0, 0, 0);                        \
            acc[nt] = __builtin_amdgcn_mfma_f32_16x16x32_bf16(             \
                av1, wf_[1][nt], acc[nt], 0, 0, 0);                        \
        }                                                                  \
        _Pragma("unroll")                                                  \
        for (int nt = 0; nt < 5; ++nt)                                     \
            _Pragma("unroll")                                              \
            for (int r = 0; r < 4; ++r) {                                  \
                float sg = frcp(1.f + fexp2(-acc[nt][r]));                 \
                (DST_)[(g4 * 4 + r) * 104 + nt * 16 + ln] = b16bits(sg);   \
            }                                                              \
    } while (0)

#define AFREAD(SRC_) do {                                                  \
        af0 = *(const bf16x8*)((SRC_) + ln * 104 + g4 * 8);                \
        af1 = *(const bf16x8*)((SRC_) + ln * 104 + 32 + g4 * 8);           \
        af2 = *(const bf16x8*)((SRC_) + ln * 104 + 64 + g4 * 8);           \
    } while (0)

#define L2L3(tile_) do {                                                   \
        f32x4 acc2[3];                                                     \
        _Pragma("unroll")                                                  \
        for (int nt = 0; nt < 3; ++nt)                                     \
            acc2[nt] = (f32x4){b2v[nt], b2v[nt], b2v[nt], b2v[nt]};        \
        _Pragma("unroll")                                                  \
        for (int nt = 0; nt < 3; ++nt) {                                   \
            bf16x8 w0_ = *(const bf16x8*)(w2f + ((0 * 3 + nt) * 64 + l) * 8); \
            bf16x8 w1_ = *(const bf16x8*)(w2f + ((1 * 3 + nt) * 64 + l) * 8); \
            bf16x8 w2_ = *(const bf16x8*)(w2f + ((2 * 3 + nt) * 64 + l) * 8); \
            acc2[nt] = __builtin_amdgcn_mfma_f32_16x16x32_bf16(af0, w0_, acc2[nt], 0, 0, 0); \
            acc2[nt] = __builtin_amdgcn_mfma_f32_16x16x32_bf16(af1, w1_, acc2[nt], 0, 0, 0); \
            acc2[nt] = __builtin_amdgcn_mfma_f32_16x16x32_bf16(af2, w2_, acc2[nt], 0, 0, 0); \
        }                                                                  \
        _Pragma("unroll")                                                  \
        for (int r = 0; r < 4; ++r) {                                      \
            float p = w3v[0] * frcp(1.f + fexp2(-acc2[0][r]))              \
                    + w3v[1] * frcp(1.f + fexp2(-acc2[1][r]))              \
                    + w3v[2] * frcp(1.f + fexp2(-acc2[2][r]));             \
            p += __shfl_xor(p, 1); p += __shfl_xor(p, 2);                  \
            p += __shfl_xor(p, 4); p += __shfl_xor(p, 8);                  \
            if (ln == 0) {                                                 \
                int trow = (tile_) * 16 + g4 * 4 + r;                      \
                if (trow < len)                                            \
                    myred[trow] = (p + b3v) * (0.125f * LOG2E);            \
            }                                                              \
        }                                                                  \
    } while (0)

        // ---- dynamic 2-tile pipeline over ntile tiles ----
        float4 A0, A1, A2, A3, C0, C1, C2, C3;
        bf16x8 af0, af1, af2;
        LOADK(0, A0, A1, A2, A3);
        L1SIG(A0, A1, A2, A3, buf0);
        if (ntile > 1) {
            LOADK(1, C0, C1, C2, C3);
            int it = 0;
            #pragma unroll 1
            while (it + 2 < ntile) {
                AFREAD(buf0);
                L1SIG(C0, C1, C2, C3, buf1);
                LOADK(it + 2, A0, A1, A2, A3);
                L2L3(it);
                AFREAD(buf1);
                L1SIG(A0, A1, A2, A3, buf0);
                LOADK(it + 3, C0, C1, C2, C3);   // may over-prefetch: clamped
                L2L3(it + 1);
                it += 2;
            }
            if (ntile - it == 2) {
                AFREAD(buf0);
                L1SIG(C0, C1, C2, C3, buf1);
                L2L3(it);
                AFREAD(buf1);
                L2L3(it + 1);
            } else {   // ntile - it == 1
                AFREAD(buf0);
                L2L3(it);
            }
        } else {
            bf16x8 af0_, af1_, af2_;   // avoid unused-warning dance
            af0_ = af0; af1_ = af1; af2_ = af2;
            AFREAD(buf0);
            L2L3(0);
        }
#undef L1SIG
#undef AFREAD
#undef L2L3
    }

    // ------------- wave-local softmax over myred[0..255] (exp2) -----------
    float v0 = myred[l], v1 = myred[64 + l], v2 = myred[128 + l], v3 = myred[192 + l];
    float m = fmaxf(fmaxf(v0, v1), fmaxf(v2, v3));
    #pragma unroll
    for (int off = 32; off; off >>= 1) m = fmaxf(m, __shfl_xor(m, off));
    float e0 = fexp2(v0 - m), e1 = fexp2(v1 - m);
    float e2 = fexp2(v2 - m), e3 = fexp2(v3 - m);
    float s = (e0 + e1) + (e2 + e3);
    #pragma unroll
    for (int off = 32; off; off >>= 1) s += __shfl_xor(s, off);
    const float is_ = frcp(s);
    myred[l] = e0 * is_; myred[64 + l] = e1 * is_;
    myred[128 + l] = e2 * is_; myred[192 + l] = e3 * is_;

    // -------- output: lane owns d-quad, t = g4 (mod 4), stop at len --------
    {
        const int obound = (len == 0) ? 200 : len;   // attn[t>=len]=0 if len>0
        float4 oq = {0.f, 0.f, 0.f, 0.f};
        #pragma unroll 4
        for (int t = g4; t < obound; t += 4) {
            float w = myred[t];
            float4 kv = *(const float4*)(kb + t * 64 + 4 * ln);
            oq.x = fmaf(w, kv.x, oq.x); oq.y = fmaf(w, kv.y, oq.y);
            oq.z = fmaf(w, kv.z, oq.z); oq.w = fmaf(w, kv.w, oq.w);
        }
        oq.x += __shfl_xor(oq.x, 16); oq.x += __shfl_xor(oq.x, 32);
        oq.y += __shfl_xor(oq.y, 16); oq.y += __shfl_xor(oq.y, 32);
        oq.z += __shfl_xor(oq.z, 16); oq.z += __shfl_xor(oq.z, 32);
        oq.w += __shfl_xor(oq.w, 16); oq.w += __shfl_xor(oq.w, 32);
        if (g4 == 0)
            *(float4*)(out + b * 64 + 4 * ln) = oq;
    }
#undef LOADK
}

extern "C" void kernel_launch(void* const* d_in, const int* in_sizes, int n_in,
                              void* d_out, int out_size, void* d_ws, size_t ws_size,
                              hipStream_t stream) {
    const float* q    = (const float*)d_in[0];
    const float* keys = (const float*)d_in[1];
    const int*   kl   = (const int*)d_in[2];
    const float* W1   = (const float*)d_in[3];
    const float* b1   = (const float*)d_in[4];
    const float* W2   = (const float*)d_in[5];
    const float* b2   = (const float*)d_in[6];
    const float* W3   = (const float*)d_in[7];
    const float* b3   = (const float*)d_in[8];

    unsigned short* w1f  = (unsigned short*)d_ws;           // 10240 bf16
    unsigned short* w2f  = w1f + 10240;                     //  4608 bf16
    unsigned short* wqff = w2f + 4608;                      //  5120 bf16

    fold_weights<<<(19968 + 255) / 256, 256, 0, stream>>>(W1, W2, w1f, w2f, wqff);
    din_attn<<<B_ / 4, NT, 0, stream>>>(q, keys, kl, w1f, w2f, wqff, b1, b2,
                                        W3, b3, (float*)d_out);
}